// Round 2
// baseline (2746.169 us; speedup 1.0000x reference)
//
#include <hip/hip_runtime.h>
#include <hip/hip_bf16.h>

// Problem constants
#define N_NODES 10000
#define N_EDGES 128000
constexpr int C = 128;
constexpr int A = 10;

constexpr float INV_SQRT_C  = 0.08838834764831845f;   // 1/sqrt(128)
constexpr float INV_SQRT_R  = 0.35355339059327373f;   // 1/sqrt(8)
constexpr float INV_SQRT_64 = 0.125f;                 // 1/sqrt(64)
constexpr float INV_SQRT_CA = 0.027950849718747374f;  // 1/sqrt(1280)
constexpr float INV_SQRT_2C = 0.0625f;                // 1/sqrt(256)
constexpr float INV_SQRT_3  = 0.57735026918962576f;

__device__ __forceinline__ float silu_f(float x) { return x / (1.0f + __expf(-x)); }

// ---------------------------------------------------------------------------
// K1: H[n, u*4+0] = h0[n,u],  H[n, u*4+1+k] = h1[n,u,k]
// ---------------------------------------------------------------------------
__global__ __launch_bounds__(256) void k_node_up(
    const float* __restrict__ nf, const float* __restrict__ Wu0,
    const float* __restrict__ Wu1, float* __restrict__ H) {
  __shared__ __align__(16) float xs[8][C][4];
  const int t = threadIdx.x;
  const int n0 = blockIdx.x * 8;
  for (int idx = t; idx < 8 * 512; idx += 256) {
    const int nn = idx >> 9, q = idx & 511;
    const float val = nf[(size_t)(n0 + nn) * 512 + q];
    if (q < C) xs[nn][q][0] = val;
    else { const int r = q - C; xs[nn][r / 3][1 + r % 3] = val; }
  }
  __syncthreads();
  const int g = t >> 7, v = t & 127;
  float acc[4][4] = {};
  for (int u = 0; u < C; ++u) {
    const float w0 = Wu0[u * C + v];
    const float w1 = Wu1[u * C + v];
#pragma unroll
    for (int nn = 0; nn < 4; ++nn) {
      const float4 xv = *(const float4*)&xs[g * 4 + nn][u][0];
      acc[nn][0] = fmaf(xv.x, w0, acc[nn][0]);
      acc[nn][1] = fmaf(xv.y, w1, acc[nn][1]);
      acc[nn][2] = fmaf(xv.z, w1, acc[nn][2]);
      acc[nn][3] = fmaf(xv.w, w1, acc[nn][3]);
    }
  }
#pragma unroll
  for (int nn = 0; nn < 4; ++nn) {
    const int n = n0 + g * 4 + nn;
    float4 o;
    o.x = acc[nn][0] * INV_SQRT_C; o.y = acc[nn][1] * INV_SQRT_C;
    o.z = acc[nn][2] * INV_SQRT_C; o.w = acc[nn][3] * INV_SQRT_C;
    *(float4*)&H[(size_t)n * 512 + v * 4] = o;
  }
}

// ---------------------------------------------------------------------------
// K2: skip connection sc -> second output (unchanged, passed last round)
// ---------------------------------------------------------------------------
__global__ __launch_bounds__(256) void k_skip(
    const float* __restrict__ nf, const float* __restrict__ attrs,
    const float* __restrict__ Ws0, const float* __restrict__ Ws1,
    float* __restrict__ sc_out) {
  __shared__ __align__(16) float xs[8][C][4];
  __shared__ float at[8][A];
  const int t = threadIdx.x;
  const int n0 = blockIdx.x * 8;
  for (int idx = t; idx < 8 * 512; idx += 256) {
    const int nn = idx >> 9, q = idx & 511;
    const float val = nf[(size_t)(n0 + nn) * 512 + q];
    if (q < C) xs[nn][q][0] = val;
    else { const int r = q - C; xs[nn][r / 3][1 + r % 3] = val; }
  }
  for (int idx = t; idx < 8 * A; idx += 256)
    at[idx / A][idx % A] = attrs[(size_t)(n0 + idx / A) * A + idx % A];
  __syncthreads();
  const int g = t >> 7, v = t & 127;
  float acc[4][4] = {};
  for (int u0 = 0; u0 < C; u0 += 4) {
    float4 xv[4][4];
#pragma unroll
    for (int nn = 0; nn < 4; ++nn)
#pragma unroll
      for (int j = 0; j < 4; ++j)
        xv[nn][j] = *(const float4*)&xs[g * 4 + nn][u0 + j][0];
#pragma unroll 2
    for (int a = 0; a < A; ++a) {
      float aa[4];
#pragma unroll
      for (int nn = 0; nn < 4; ++nn) aa[nn] = at[g * 4 + nn][a];
#pragma unroll
      for (int j = 0; j < 4; ++j) {
        const float w0 = Ws0[((u0 + j) * A + a) * C + v];
        const float w1 = Ws1[((u0 + j) * A + a) * C + v];
#pragma unroll
        for (int nn = 0; nn < 4; ++nn) {
          const float t0 = aa[nn] * w0;
          const float t1 = aa[nn] * w1;
          acc[nn][0] = fmaf(xv[nn][j].x, t0, acc[nn][0]);
          acc[nn][1] = fmaf(xv[nn][j].y, t1, acc[nn][1]);
          acc[nn][2] = fmaf(xv[nn][j].z, t1, acc[nn][2]);
          acc[nn][3] = fmaf(xv[nn][j].w, t1, acc[nn][3]);
        }
      }
    }
  }
#pragma unroll
  for (int nn = 0; nn < 4; ++nn) {
    const int n = n0 + g * 4 + nn;
    float* row = sc_out + (size_t)n * 512;
    row[v]             = acc[nn][0] * INV_SQRT_CA;
    row[C + v * 3 + 0] = acc[nn][1] * INV_SQRT_CA;
    row[C + v * 3 + 1] = acc[nn][2] * INV_SQRT_CA;
    row[C + v * 3 + 2] = acc[nn][3] * INV_SQRT_CA;
  }
}

// ---------------------------------------------------------------------------
// Sort-by-receiver infrastructure: histogram -> scan -> scatter
// ---------------------------------------------------------------------------
__global__ __launch_bounds__(256) void k_hist(const int* __restrict__ eidx,
                                              int* __restrict__ counts) {
  const int e = blockIdx.x * 256 + threadIdx.x;
  if (e < N_EDGES) atomicAdd(&counts[eidx[N_EDGES + e]], 1);
}

__global__ __launch_bounds__(1024) void k_scan(const int* __restrict__ counts,
                                               int* __restrict__ offsets,
                                               int* __restrict__ cursor) {
  __shared__ int part[1024];
  const int t = threadIdx.x;
  int local[10];
  int s = 0;
#pragma unroll
  for (int i = 0; i < 10; ++i) {
    const int idx = t * 10 + i;
    const int c = (idx < N_NODES) ? counts[idx] : 0;
    local[i] = s;
    s += c;
  }
  part[t] = s;
  __syncthreads();
  for (int off = 1; off < 1024; off <<= 1) {
    const int add = (t >= off) ? part[t - off] : 0;
    __syncthreads();
    part[t] += add;
    __syncthreads();
  }
  const int pre = (t > 0) ? part[t - 1] : 0;
#pragma unroll
  for (int i = 0; i < 10; ++i) {
    const int idx = t * 10 + i;
    if (idx < N_NODES) {
      const int o = pre + local[i];
      offsets[idx] = o;
      cursor[idx] = o;
    }
  }
  if (t == 1023) offsets[N_NODES] = part[1023];
}

__global__ __launch_bounds__(256) void k_scatter(const int* __restrict__ eidx,
                                                 int* __restrict__ cursor,
                                                 int* __restrict__ perm) {
  const int e = blockIdx.x * 256 + threadIdx.x;
  if (e < N_EDGES) {
    const int pos = atomicAdd(&cursor[eidx[N_EDGES + e]], 1);
    perm[pos] = e;
  }
}

// ---------------------------------------------------------------------------
// K3: fused edge-MLP + gather + register-accumulate + output GEMM.
// One workgroup per 4 receiver nodes. Edges arrive sorted by receiver via
// perm; accumulation is in VGPRs (thread t owns M elements [4t, 4t+4) of each
// of its 4 nodes). No global atomics. wls LDS is reused as Msh for the GEMM.
// ---------------------------------------------------------------------------
__global__ __launch_bounds__(256) void k_gather(
    const int* __restrict__ perm, const int* __restrict__ offsets,
    const float* __restrict__ ef_g, const float* __restrict__ ea_g,
    const int* __restrict__ eidx,
    const float* __restrict__ R0, const float* __restrict__ R1,
    const float* __restrict__ R2, const float* __restrict__ R3,
    const float* __restrict__ Wd,
    const float* __restrict__ H,
    const float* __restrict__ Wl0, const float* __restrict__ Wl1,
    float* __restrict__ out) {
  __shared__ __align__(16) float efs[16][8];
  __shared__ float ys[16][4];
  __shared__ int es[16], sn[16], nis[16];
  __shared__ int offs[5];
  __shared__ __align__(16) float b0[16][64];
  __shared__ __align__(16) float b1[16][64];
  __shared__ __align__(16) float wls[16][512];   // 32 KB; reused as Msh[4][1024]
  __shared__ float densAcc[4];

  const int t = threadIdx.x;
  const int n0 = blockIdx.x * 4;
  if (t < 5) offs[t] = offsets[n0 + t];
  if (t < 4) densAcc[t] = 0.0f;
  __syncthreads();
  const int start = offs[0], end = offs[4];

  float acc[4][4] = {};  // [node][component] — this thread's 4 M-entries/node
  const int u = t & 127;
  const int half = t >> 7;

  for (int base = start; base < end; base += 16) {
    __syncthreads();  // protect prev-iteration LDS reads
    // stage 0: edge metadata
    if (t < 16) {
      const int pos = base + t;
      const bool valid = pos < end;
      const int pe = valid ? perm[pos] : perm[end - 1];
      es[t] = pe;
      sn[t] = eidx[pe];
      nis[t] = valid
          ? ((pos >= offs[1]) + (pos >= offs[2]) + (pos >= offs[3]))
          : 4;
    }
    __syncthreads();
    // stage 1: load edge feats + attrs
    if (t < 128) efs[t >> 3][t & 7] = ef_g[(size_t)es[t >> 3] * 8 + (t & 7)];
    else if (t < 192) {
      const int i = t - 128;
      ys[i >> 2][i & 3] = ea_g[(size_t)es[i >> 2] * 4 + (i & 3)];
    }
    __syncthreads();
    // L1: 8 -> 64 (+ density on lanes 0..15)
    {
      const int j = t & 63;
#pragma unroll
      for (int r = 0; r < 4; ++r) {
        const int e = (t >> 6) + r * 4;
        float s = 0.f;
#pragma unroll
        for (int i = 0; i < 8; ++i) s = fmaf(efs[e][i], R0[i * 64 + j], s);
        b0[e][j] = silu_f(s * INV_SQRT_R);
      }
      if (t < 16 && nis[t] < 4) {
        float s = 0.f;
#pragma unroll
        for (int i = 0; i < 8; ++i) s = fmaf(efs[t][i], Wd[i], s);
        s *= INV_SQRT_R;
        atomicAdd(&densAcc[nis[t]], tanhf(s * s));  // LDS atomic
      }
    }
    __syncthreads();
    // L2: 64 -> 64 (b0 -> b1)
    {
      const int e = t >> 4, jg = t & 15;
      float a2[4] = {};
      for (int i0 = 0; i0 < 64; i0 += 4) {
        const float4 b = *(const float4*)&b0[e][i0];
#pragma unroll
        for (int ii = 0; ii < 4; ++ii) {
          const float bv = (&b.x)[ii];
#pragma unroll
          for (int q = 0; q < 4; ++q)
            a2[q] = fmaf(bv, R1[(i0 + ii) * 64 + jg + 16 * q], a2[q]);
        }
      }
#pragma unroll
      for (int q = 0; q < 4; ++q) b1[e][jg + 16 * q] = silu_f(a2[q] * INV_SQRT_64);
    }
    __syncthreads();
    // L3: 64 -> 64 (b1 -> b0)
    {
      const int e = t >> 4, jg = t & 15;
      float a3[4] = {};
      for (int i0 = 0; i0 < 64; i0 += 4) {
        const float4 b = *(const float4*)&b1[e][i0];
#pragma unroll
        for (int ii = 0; ii < 4; ++ii) {
          const float bv = (&b.x)[ii];
#pragma unroll
          for (int q = 0; q < 4; ++q)
            a3[q] = fmaf(bv, R2[(i0 + ii) * 64 + jg + 16 * q], a3[q]);
        }
      }
      __syncthreads();
#pragma unroll
      for (int q = 0; q < 4; ++q) b0[e][jg + 16 * q] = silu_f(a3[q] * INV_SQRT_64);
    }
    __syncthreads();
    // L4: 64 -> 512 into wls
    {
      const int eg = t >> 7;
      const int jg = t & 127;
      float wacc[8][4] = {};
      for (int i0 = 0; i0 < 64; i0 += 4) {
        float4 bb[8];
#pragma unroll
        for (int e = 0; e < 8; ++e) bb[e] = *(const float4*)&b0[eg * 8 + e][i0];
#pragma unroll
        for (int ii = 0; ii < 4; ++ii) {
          const float4 r4 = *(const float4*)&R3[(size_t)(i0 + ii) * 512 + jg * 4];
#pragma unroll
          for (int e = 0; e < 8; ++e) {
            const float bv = (&bb[e].x)[ii];
            wacc[e][0] = fmaf(bv, r4.x, wacc[e][0]);
            wacc[e][1] = fmaf(bv, r4.y, wacc[e][1]);
            wacc[e][2] = fmaf(bv, r4.z, wacc[e][2]);
            wacc[e][3] = fmaf(bv, r4.w, wacc[e][3]);
          }
        }
      }
#pragma unroll
      for (int e = 0; e < 8; ++e) {
        float4 o;
        o.x = wacc[e][0] * INV_SQRT_64; o.y = wacc[e][1] * INV_SQRT_64;
        o.z = wacc[e][2] * INV_SQRT_64; o.w = wacc[e][3] * INV_SQRT_64;
        *(float4*)&wls[eg * 8 + e][jg * 4] = o;
      }
    }
    __syncthreads();
    // accumulate: all 256 threads process each edge together (4 vals/thread)
#pragma unroll 4
    for (int el = 0; el < 16; ++el) {
      const int ni = nis[el];
      if (ni >= 4) continue;
      const int s = sn[el];
      const float4 h4 = *(const float4*)&H[(size_t)s * 512 + u * 4];
      const float y0 = ys[el][0];
      const float y1x = ys[el][1], y1y = ys[el][2], y1z = ys[el][3];
      float v0, v1, v2, v3;
      if (half == 0) {
        const float w1v = wls[el][u], w2v = wls[el][128 + u];
        v0 = w1v * h4.x * y0;
        const float c1 = w2v * h4.x;
        v1 = c1 * y1x; v2 = c1 * y1y; v3 = c1 * y1z;
      } else {
        const float w3v = wls[el][256 + u], w4v = wls[el][384 + u];
        const float dt = h4.y * y1x + h4.z * y1y + h4.w * y1z;
        v0 = w4v * dt * INV_SQRT_3;
        const float c3 = w3v * y0;
        v1 = c3 * h4.y; v2 = c3 * h4.z; v3 = c3 * h4.w;
      }
      if (ni == 0)      { acc[0][0]+=v0; acc[0][1]+=v1; acc[0][2]+=v2; acc[0][3]+=v3; }
      else if (ni == 1) { acc[1][0]+=v0; acc[1][1]+=v1; acc[1][2]+=v2; acc[1][3]+=v3; }
      else if (ni == 2) { acc[2][0]+=v0; acc[2][1]+=v1; acc[2][2]+=v2; acc[2][3]+=v3; }
      else              { acc[3][0]+=v0; acc[3][1]+=v1; acc[3][2]+=v2; acc[3][3]+=v3; }
    }
  }

  // ---- fused output GEMM ----
  __syncthreads();  // wls now dead; reuse as Msh
  float (*Msh)[1024] = (float (*)[1024])wls;
#pragma unroll
  for (int j = 0; j < 4; ++j) {
    float4 o = make_float4(acc[j][0], acc[j][1], acc[j][2], acc[j][3]);
    *(float4*)&Msh[j][half * 512 + u * 4] = o;
  }
  __syncthreads();
  // out[n, v, c]: half 0 -> comps {0,1} = (out0, out1_k0); half 1 -> {2,3}
  const int v = u;
  float o2[4][2] = {};
  for (int p = 0; p < 256; ++p) {
    const float wl0 = Wl0[p * 128 + v];
    const float wl1 = Wl1[p * 128 + v];
    const float wsel = (half == 0) ? wl0 : wl1;
#pragma unroll
    for (int j = 0; j < 4; ++j) {
      const float2 m = *(const float2*)&Msh[j][p * 4 + half * 2];
      o2[j][0] = fmaf(m.x, wsel, o2[j][0]);
      o2[j][1] = fmaf(m.y, wl1, o2[j][1]);
    }
  }
#pragma unroll
  for (int j = 0; j < 4; ++j) {
    const int n = n0 + j;
    const float sc = INV_SQRT_2C / (densAcc[j] + 1.0f);
    float2 ov = make_float2(o2[j][0] * sc, o2[j][1] * sc);
    *(float2*)&out[(size_t)n * 512 + v * 4 + half * 2] = ov;
  }
}

// ---------------------------------------------------------------------------
extern "C" void kernel_launch(void* const* d_in, const int* in_sizes, int n_in,
                              void* d_out, int out_size, void* d_ws, size_t ws_size,
                              hipStream_t stream) {
  const float* node_attrs = (const float*)d_in[0];
  const float* node_feats = (const float*)d_in[1];
  const float* edge_attrs = (const float*)d_in[2];
  const float* edge_feats = (const float*)d_in[3];
  const int*   edge_index = (const int*)d_in[4];
  const float* W_up0 = (const float*)d_in[5];
  const float* W_up1 = (const float*)d_in[6];
  const float* R0 = (const float*)d_in[7];
  const float* R1 = (const float*)d_in[8];
  const float* R2 = (const float*)d_in[9];
  const float* R3 = (const float*)d_in[10];
  const float* Wd  = (const float*)d_in[11];
  const float* Wl0 = (const float*)d_in[12];
  const float* Wl1 = (const float*)d_in[13];
  const float* Ws0 = (const float*)d_in[14];
  const float* Ws1 = (const float*)d_in[15];
  float* out = (float*)d_out;

  // Workspace: H (N*512 f32) | counts | offsets | cursor | perm  (~21.2 MB)
  float* H = (float*)d_ws;
  int* counts  = (int*)(H + (size_t)N_NODES * 512);
  int* offsets = counts + 10016;
  int* cursor  = offsets + 10016;
  int* perm    = cursor + 10016;

  hipMemsetAsync(counts, 0, 10016 * sizeof(int), stream);

  k_node_up<<<N_NODES / 8, 256, 0, stream>>>(node_feats, W_up0, W_up1, H);
  k_hist<<<(N_EDGES + 255) / 256, 256, 0, stream>>>(edge_index, counts);
  k_scan<<<1, 1024, 0, stream>>>(counts, offsets, cursor);
  k_scatter<<<(N_EDGES + 255) / 256, 256, 0, stream>>>(edge_index, cursor, perm);
  k_gather<<<N_NODES / 4, 256, 0, stream>>>(perm, offsets, edge_feats, edge_attrs,
                                            edge_index, R0, R1, R2, R3, Wd, H,
                                            Wl0, Wl1, out);
  k_skip<<<N_NODES / 8, 256, 0, stream>>>(node_feats, node_attrs, Ws0, Ws1,
                                          out + (size_t)N_NODES * 512);
}

// Round 3
// 830.090 us; speedup vs baseline: 3.3083x; 3.3083x over previous
//
#include <hip/hip_runtime.h>
#include <hip/hip_bf16.h>
#include <hip/hip_fp16.h>

// Problem constants
#define N_NODES 10000
#define N_EDGES 128000
constexpr int C = 128;
constexpr int A = 10;

constexpr float INV_SQRT_C  = 0.08838834764831845f;   // 1/sqrt(128)
constexpr float INV_SQRT_R  = 0.35355339059327373f;   // 1/sqrt(8)
constexpr float INV_SQRT_64 = 0.125f;                 // 1/sqrt(64)
constexpr float INV_SQRT_CA = 0.027950849718747374f;  // 1/sqrt(1280)
constexpr float INV_SQRT_2C = 0.0625f;                // 1/sqrt(256)
constexpr float INV_SQRT_3  = 0.57735026918962576f;

__device__ __forceinline__ float silu_f(float x) { return x / (1.0f + __expf(-x)); }

__device__ __forceinline__ void atomic_add_f32(float* p, float v) {
  __hip_atomic_fetch_add(p, v, __ATOMIC_RELAXED, __HIP_MEMORY_SCOPE_AGENT);
}

// ---------------------------------------------------------------------------
// K1: H[n, u*4+0] = h0[n,u],  H[n, u*4+1+k] = h1[n,u,k]
// ---------------------------------------------------------------------------
__global__ __launch_bounds__(256) void k_node_up(
    const float* __restrict__ nf, const float* __restrict__ Wu0,
    const float* __restrict__ Wu1, float* __restrict__ H) {
  __shared__ __align__(16) float xs[8][C][4];
  const int t = threadIdx.x;
  const int n0 = blockIdx.x * 8;
  for (int idx = t; idx < 8 * 512; idx += 256) {
    const int nn = idx >> 9, q = idx & 511;
    const float val = nf[(size_t)(n0 + nn) * 512 + q];
    if (q < C) xs[nn][q][0] = val;
    else { const int r = q - C; xs[nn][r / 3][1 + r % 3] = val; }
  }
  __syncthreads();
  const int g = t >> 7, v = t & 127;
  float acc[4][4] = {};
  for (int u = 0; u < C; ++u) {
    const float w0 = Wu0[u * C + v];
    const float w1 = Wu1[u * C + v];
#pragma unroll
    for (int nn = 0; nn < 4; ++nn) {
      const float4 xv = *(const float4*)&xs[g * 4 + nn][u][0];
      acc[nn][0] = fmaf(xv.x, w0, acc[nn][0]);
      acc[nn][1] = fmaf(xv.y, w1, acc[nn][1]);
      acc[nn][2] = fmaf(xv.z, w1, acc[nn][2]);
      acc[nn][3] = fmaf(xv.w, w1, acc[nn][3]);
    }
  }
#pragma unroll
  for (int nn = 0; nn < 4; ++nn) {
    const int n = n0 + g * 4 + nn;
    float4 o;
    o.x = acc[nn][0] * INV_SQRT_C; o.y = acc[nn][1] * INV_SQRT_C;
    o.z = acc[nn][2] * INV_SQRT_C; o.w = acc[nn][3] * INV_SQRT_C;
    *(float4*)&H[(size_t)n * 512 + v * 4] = o;
  }
}

// ---------------------------------------------------------------------------
// K2: skip connection sc -> second output
// ---------------------------------------------------------------------------
__global__ __launch_bounds__(256) void k_skip(
    const float* __restrict__ nf, const float* __restrict__ attrs,
    const float* __restrict__ Ws0, const float* __restrict__ Ws1,
    float* __restrict__ sc_out) {
  __shared__ __align__(16) float xs[8][C][4];
  __shared__ float at[8][A];
  const int t = threadIdx.x;
  const int n0 = blockIdx.x * 8;
  for (int idx = t; idx < 8 * 512; idx += 256) {
    const int nn = idx >> 9, q = idx & 511;
    const float val = nf[(size_t)(n0 + nn) * 512 + q];
    if (q < C) xs[nn][q][0] = val;
    else { const int r = q - C; xs[nn][r / 3][1 + r % 3] = val; }
  }
  for (int idx = t; idx < 8 * A; idx += 256)
    at[idx / A][idx % A] = attrs[(size_t)(n0 + idx / A) * A + idx % A];
  __syncthreads();
  const int g = t >> 7, v = t & 127;
  float acc[4][4] = {};
  for (int u0 = 0; u0 < C; u0 += 4) {
    float4 xv[4][4];
#pragma unroll
    for (int nn = 0; nn < 4; ++nn)
#pragma unroll
      for (int j = 0; j < 4; ++j)
        xv[nn][j] = *(const float4*)&xs[g * 4 + nn][u0 + j][0];
#pragma unroll 2
    for (int a = 0; a < A; ++a) {
      float aa[4];
#pragma unroll
      for (int nn = 0; nn < 4; ++nn) aa[nn] = at[g * 4 + nn][a];
#pragma unroll
      for (int j = 0; j < 4; ++j) {
        const float w0 = Ws0[((u0 + j) * A + a) * C + v];
        const float w1 = Ws1[((u0 + j) * A + a) * C + v];
#pragma unroll
        for (int nn = 0; nn < 4; ++nn) {
          const float t0 = aa[nn] * w0;
          const float t1 = aa[nn] * w1;
          acc[nn][0] = fmaf(xv[nn][j].x, t0, acc[nn][0]);
          acc[nn][1] = fmaf(xv[nn][j].y, t1, acc[nn][1]);
          acc[nn][2] = fmaf(xv[nn][j].z, t1, acc[nn][2]);
          acc[nn][3] = fmaf(xv[nn][j].w, t1, acc[nn][3]);
        }
      }
    }
  }
#pragma unroll
  for (int nn = 0; nn < 4; ++nn) {
    const int n = n0 + g * 4 + nn;
    float* row = sc_out + (size_t)n * 512;
    row[v]             = acc[nn][0] * INV_SQRT_CA;
    row[C + v * 3 + 0] = acc[nn][1] * INV_SQRT_CA;
    row[C + v * 3 + 1] = acc[nn][2] * INV_SQRT_CA;
    row[C + v * 3 + 2] = acc[nn][3] * INV_SQRT_CA;
  }
}

// ---------------------------------------------------------------------------
// Sort-by-receiver: histogram -> scan -> scatter (fills sorted aux arrays)
// ---------------------------------------------------------------------------
__global__ __launch_bounds__(256) void k_hist(const int* __restrict__ eidx,
                                              int* __restrict__ counts) {
  const int e = blockIdx.x * 256 + threadIdx.x;
  if (e < N_EDGES) atomicAdd(&counts[eidx[N_EDGES + e]], 1);
}

__global__ __launch_bounds__(1024) void k_scan(const int* __restrict__ counts,
                                               int* __restrict__ offsets,
                                               int* __restrict__ cursor) {
  __shared__ int part[1024];
  const int t = threadIdx.x;
  int local[10];
  int s = 0;
#pragma unroll
  for (int i = 0; i < 10; ++i) {
    const int idx = t * 10 + i;
    const int c = (idx < N_NODES) ? counts[idx] : 0;
    local[i] = s;
    s += c;
  }
  part[t] = s;
  __syncthreads();
  for (int off = 1; off < 1024; off <<= 1) {
    const int add = (t >= off) ? part[t - off] : 0;
    __syncthreads();
    part[t] += add;
    __syncthreads();
  }
  const int pre = (t > 0) ? part[t - 1] : 0;
#pragma unroll
  for (int i = 0; i < 10; ++i) {
    const int idx = t * 10 + i;
    if (idx < N_NODES) {
      const int o = pre + local[i];
      offsets[idx] = o;
      cursor[idx] = o;
    }
  }
  if (t == 1023) offsets[N_NODES] = part[1023];
}

__global__ __launch_bounds__(256) void k_scatter(
    const int* __restrict__ eidx, const float* __restrict__ ea_g,
    int* __restrict__ cursor, int* __restrict__ perm,
    int* __restrict__ snd_s, int* __restrict__ rcv_s,
    float* __restrict__ ea_s) {
  const int e = blockIdx.x * 256 + threadIdx.x;
  if (e < N_EDGES) {
    const int r = eidx[N_EDGES + e];
    const int pos = atomicAdd(&cursor[r], 1);
    perm[pos] = e;
    snd_s[pos] = eidx[e];
    rcv_s[pos] = r;
    ((float4*)ea_s)[pos] = ((const float4*)ea_g)[e];
  }
}

// ---------------------------------------------------------------------------
// K3: edge MLP (8->64->64->64->512), edges in SORTED order, W output as fp16.
// Also accumulates density via global atomics (128K total, cheap).
// 16 edges / 256-thread block, 8000 blocks. No cross-chunk state.
// ---------------------------------------------------------------------------
__global__ __launch_bounds__(256) void k_mlp(
    const int* __restrict__ perm, const int* __restrict__ rcv_s,
    const float* __restrict__ ef_g,
    const float* __restrict__ R0, const float* __restrict__ R1,
    const float* __restrict__ R2, const float* __restrict__ R3,
    const float* __restrict__ Wd,
    __half* __restrict__ W, float* __restrict__ density) {
  __shared__ __align__(16) float efs[16][8];
  __shared__ __align__(16) float b0[16][64];
  __shared__ __align__(16) float b1[16][64];
  __shared__ int es[16];
  const int t = threadIdx.x;
  const int e0 = blockIdx.x * 16;

  if (t < 16) es[t] = perm[e0 + t];
  __syncthreads();
  if (t < 128) efs[t >> 3][t & 7] = ef_g[(size_t)es[t >> 3] * 8 + (t & 7)];
  __syncthreads();

  // density (one thread per edge; receiver from sorted aux)
  if (t < 16) {
    float s = 0.f;
#pragma unroll
    for (int i = 0; i < 8; ++i) s = fmaf(efs[t][i], Wd[i], s);
    s *= INV_SQRT_R;
    atomic_add_f32(&density[rcv_s[e0 + t]], tanhf(s * s));
  }

  // L1: 8 -> 64
  {
    const int j = t & 63;
#pragma unroll
    for (int r = 0; r < 4; ++r) {
      const int e = (t >> 6) + r * 4;
      float s = 0.f;
#pragma unroll
      for (int i = 0; i < 8; ++i) s = fmaf(efs[e][i], R0[i * 64 + j], s);
      b0[e][j] = silu_f(s * INV_SQRT_R);
    }
  }
  __syncthreads();

  // L2: 64 -> 64 (b0 -> b1)
  {
    const int e = t >> 4, jg = t & 15;
    float a2[4] = {};
    for (int i0 = 0; i0 < 64; i0 += 4) {
      const float4 b = *(const float4*)&b0[e][i0];
#pragma unroll
      for (int ii = 0; ii < 4; ++ii) {
        const float bv = (&b.x)[ii];
#pragma unroll
        for (int q = 0; q < 4; ++q)
          a2[q] = fmaf(bv, R1[(i0 + ii) * 64 + jg + 16 * q], a2[q]);
      }
    }
#pragma unroll
    for (int q = 0; q < 4; ++q) b1[e][jg + 16 * q] = silu_f(a2[q] * INV_SQRT_64);
  }
  __syncthreads();

  // L3: 64 -> 64 (b1 -> b0)
  {
    const int e = t >> 4, jg = t & 15;
    float a3[4] = {};
    for (int i0 = 0; i0 < 64; i0 += 4) {
      const float4 b = *(const float4*)&b1[e][i0];
#pragma unroll
      for (int ii = 0; ii < 4; ++ii) {
        const float bv = (&b.x)[ii];
#pragma unroll
        for (int q = 0; q < 4; ++q)
          a3[q] = fmaf(bv, R2[(i0 + ii) * 64 + jg + 16 * q], a3[q]);
      }
    }
    __syncthreads();
#pragma unroll
    for (int q = 0; q < 4; ++q) b0[e][jg + 16 * q] = silu_f(a3[q] * INV_SQRT_64);
  }
  __syncthreads();

  // L4: 64 -> 512, write fp16 directly to global W (sorted edge order)
  {
    const int eg = t >> 7;
    const int jg = t & 127;
    float wacc[8][4] = {};
    for (int i0 = 0; i0 < 64; i0 += 4) {
      float4 bb[8];
#pragma unroll
      for (int e = 0; e < 8; ++e) bb[e] = *(const float4*)&b0[eg * 8 + e][i0];
#pragma unroll
      for (int ii = 0; ii < 4; ++ii) {
        const float4 r4 = *(const float4*)&R3[(size_t)(i0 + ii) * 512 + jg * 4];
#pragma unroll
        for (int e = 0; e < 8; ++e) {
          const float bv = (&bb[e].x)[ii];
          wacc[e][0] = fmaf(bv, r4.x, wacc[e][0]);
          wacc[e][1] = fmaf(bv, r4.y, wacc[e][1]);
          wacc[e][2] = fmaf(bv, r4.z, wacc[e][2]);
          wacc[e][3] = fmaf(bv, r4.w, wacc[e][3]);
        }
      }
    }
#pragma unroll
    for (int e = 0; e < 8; ++e) {
      __half2 lo = __floats2half2_rn(wacc[e][0] * INV_SQRT_64, wacc[e][1] * INV_SQRT_64);
      __half2 hi = __floats2half2_rn(wacc[e][2] * INV_SQRT_64, wacc[e][3] * INV_SQRT_64);
      uint2 pk;
      pk.x = *(unsigned int*)&lo;
      pk.y = *(unsigned int*)&hi;
      *(uint2*)&W[(size_t)(e0 + eg * 8 + e) * 512 + jg * 4] = pk;
    }
  }
}

// ---------------------------------------------------------------------------
// K4: message formation + segmented reduction over sorted edges.
// 64 edges per 256-thread block. Thread t owns 4 components (u = t&127,
// half = t>>7) of the running segment sum. Interior segments -> plain store;
// boundary segments -> atomicAdd. M layout: [n][p*4+j], p<128 from half0,
// p>=128 from half1 (matches k_out).
// ---------------------------------------------------------------------------
__global__ __launch_bounds__(256) void k_message(
    const int* __restrict__ snd_s, const int* __restrict__ rcv_s,
    const int* __restrict__ offsets, const float* __restrict__ ea_s,
    const __half* __restrict__ W, const float* __restrict__ H,
    float* __restrict__ M) {
  __shared__ int sn[64], rc[64];
  __shared__ __align__(16) float ys[64][4];
  const int t = threadIdx.x;
  const int base = blockIdx.x * 64;
  if (t < 64) { sn[t] = snd_s[base + t]; rc[t] = rcv_s[base + t]; }
  ys[t >> 2][t & 3] = ea_s[(size_t)base * 4 + t];
  __syncthreads();

  const int u = t & 127, half = t >> 7;
  float a0 = 0.f, a1 = 0.f, a2 = 0.f, a3 = 0.f;
  int cur = rc[0];

  auto flush = [&](int n) {
    const int s0 = offsets[n], s1 = offsets[n + 1];
    float* Mp = &M[(size_t)n * 1024 + (half << 9) + (u << 2)];
    if (s0 >= base && s1 <= base + 64) {
      *(float4*)Mp = make_float4(a0, a1, a2, a3);
    } else {
      atomic_add_f32(Mp + 0, a0);
      atomic_add_f32(Mp + 1, a1);
      atomic_add_f32(Mp + 2, a2);
      atomic_add_f32(Mp + 3, a3);
    }
  };

  for (int e = 0; e < 64; ++e) {
    const int n = rc[e];
    if (n != cur) {  // wave-uniform branch
      flush(cur);
      a0 = a1 = a2 = a3 = 0.f;
      cur = n;
    }
    const int s = sn[e];
    const float4 h4 = *(const float4*)&H[(size_t)s * 512 + (u << 2)];
    const float y0 = ys[e][0];
    const float y1x = ys[e][1], y1y = ys[e][2], y1z = ys[e][3];
    const size_t wb = (size_t)(base + e) * 512;
    if (half == 0) {
      const float w1v = __half2float(W[wb + u]);
      const float w2v = __half2float(W[wb + 128 + u]);
      a0 = fmaf(w1v * h4.x, y0, a0);
      const float c1 = w2v * h4.x;
      a1 = fmaf(c1, y1x, a1);
      a2 = fmaf(c1, y1y, a2);
      a3 = fmaf(c1, y1z, a3);
    } else {
      const float w3v = __half2float(W[wb + 256 + u]);
      const float w4v = __half2float(W[wb + 384 + u]);
      const float dt = h4.y * y1x + h4.z * y1y + h4.w * y1z;
      a0 = fmaf(w4v * dt, INV_SQRT_3, a0);
      const float c3 = w3v * y0;
      a1 = fmaf(c3, h4.y, a1);
      a2 = fmaf(c3, h4.z, a2);
      a3 = fmaf(c3, h4.w, a3);
    }
  }
  flush(cur);
}

// ---------------------------------------------------------------------------
// K5: out0 = M0 @ Wl0 /16/denom; out1[.,.,k] = M1[...,k] @ Wl1 /16/denom
// ---------------------------------------------------------------------------
__global__ __launch_bounds__(256) void k_out(
    const float* __restrict__ M, const float* __restrict__ density,
    const float* __restrict__ Wl0, const float* __restrict__ Wl1,
    float* __restrict__ out) {
  __shared__ __align__(16) float Ms[8][256][4];  // 32 KB
  __shared__ float dens[8];
  const int t = threadIdx.x;
  const int n0 = blockIdx.x * 8;
  const float4* Msrc = (const float4*)&M[(size_t)n0 * 1024];
  float4* Mdst = (float4*)&Ms[0][0][0];
  for (int idx = t; idx < 8 * 256; idx += 256) Mdst[idx] = Msrc[idx];
  if (t < 8) dens[t] = density[n0 + t] + 1.0f;
  __syncthreads();
  const int g = t >> 7, v = t & 127;
  float acc[4][4] = {};
  for (int p0 = 0; p0 < 256; p0 += 4) {
    float4 mv[4][4];
#pragma unroll
    for (int nn = 0; nn < 4; ++nn)
#pragma unroll
      for (int j = 0; j < 4; ++j)
        mv[nn][j] = *(const float4*)&Ms[g * 4 + nn][p0 + j][0];
#pragma unroll
    for (int j = 0; j < 4; ++j) {
      const float w0 = Wl0[(p0 + j) * C + v];
      const float w1 = Wl1[(p0 + j) * C + v];
#pragma unroll
      for (int nn = 0; nn < 4; ++nn) {
        acc[nn][0] = fmaf(mv[nn][j].x, w0, acc[nn][0]);
        acc[nn][1] = fmaf(mv[nn][j].y, w1, acc[nn][1]);
        acc[nn][2] = fmaf(mv[nn][j].z, w1, acc[nn][2]);
        acc[nn][3] = fmaf(mv[nn][j].w, w1, acc[nn][3]);
      }
    }
  }
#pragma unroll
  for (int nn = 0; nn < 4; ++nn) {
    const int n = n0 + g * 4 + nn;
    const float sc = INV_SQRT_2C / dens[g * 4 + nn];
    float4 o;
    o.x = acc[nn][0] * sc; o.y = acc[nn][1] * sc;
    o.z = acc[nn][2] * sc; o.w = acc[nn][3] * sc;
    *(float4*)&out[(size_t)n * 512 + v * 4] = o;
  }
}

// ---------------------------------------------------------------------------
extern "C" void kernel_launch(void* const* d_in, const int* in_sizes, int n_in,
                              void* d_out, int out_size, void* d_ws, size_t ws_size,
                              hipStream_t stream) {
  const float* node_attrs = (const float*)d_in[0];
  const float* node_feats = (const float*)d_in[1];
  const float* edge_attrs = (const float*)d_in[2];
  const float* edge_feats = (const float*)d_in[3];
  const int*   edge_index = (const int*)d_in[4];
  const float* W_up0 = (const float*)d_in[5];
  const float* W_up1 = (const float*)d_in[6];
  const float* R0 = (const float*)d_in[7];
  const float* R1 = (const float*)d_in[8];
  const float* R2 = (const float*)d_in[9];
  const float* R3 = (const float*)d_in[10];
  const float* Wd  = (const float*)d_in[11];
  const float* Wl0 = (const float*)d_in[12];
  const float* Wl1 = (const float*)d_in[13];
  const float* Ws0 = (const float*)d_in[14];
  const float* Ws1 = (const float*)d_in[15];
  float* out = (float*)d_out;

  // Workspace layout (floats unless noted):
  // H (N*512) | M (N*1024) | density (N) | counts | offsets | cursor |
  // perm | snd_s | rcv_s (E ints each) | ea_s (E*4) | W (E*512 half)
  float* H = (float*)d_ws;
  float* M = H + (size_t)N_NODES * 512;
  float* density = M + (size_t)N_NODES * 1024;
  int* counts  = (int*)(density + 10000);
  int* offsets = counts + 10016;
  int* cursor  = offsets + 10016;
  int* perm    = cursor + 10016;
  int* snd_s   = perm + N_EDGES;
  int* rcv_s   = snd_s + N_EDGES;
  float* ea_s  = (float*)(rcv_s + N_EDGES);
  __half* W    = (__half*)(ea_s + (size_t)N_EDGES * 4);

  // zero M + density + counts (contiguous)
  hipMemsetAsync(M, 0, ((size_t)N_NODES * 1024 + 10000 + 10016) * sizeof(float),
                 stream);

  k_node_up<<<N_NODES / 8, 256, 0, stream>>>(node_feats, W_up0, W_up1, H);
  k_hist<<<(N_EDGES + 255) / 256, 256, 0, stream>>>(edge_index, counts);
  k_scan<<<1, 1024, 0, stream>>>(counts, offsets, cursor);
  k_scatter<<<(N_EDGES + 255) / 256, 256, 0, stream>>>(edge_index, edge_attrs,
                                                       cursor, perm, snd_s,
                                                       rcv_s, ea_s);
  k_mlp<<<N_EDGES / 16, 256, 0, stream>>>(perm, rcv_s, edge_feats, R0, R1, R2,
                                          R3, Wd, W, density);
  k_message<<<N_EDGES / 64, 256, 0, stream>>>(snd_s, rcv_s, offsets, ea_s, W, H,
                                              M);
  k_out<<<N_NODES / 8, 256, 0, stream>>>(M, density, Wl0, Wl1, out);
  k_skip<<<N_NODES / 8, 256, 0, stream>>>(node_feats, node_attrs, Ws0, Ws1,
                                          out + (size_t)N_NODES * 512);
}

// Round 4
// 635.243 us; speedup vs baseline: 4.3230x; 1.3067x over previous
//
#include <hip/hip_runtime.h>
#include <hip/hip_bf16.h>
#include <hip/hip_fp16.h>

// Problem constants
#define N_NODES 10000
#define N_EDGES 128000
constexpr int C = 128;
constexpr int A = 10;

constexpr float INV_SQRT_C  = 0.08838834764831845f;   // 1/sqrt(128)
constexpr float INV_SQRT_R  = 0.35355339059327373f;   // 1/sqrt(8)
constexpr float INV_SQRT_64 = 0.125f;                 // 1/sqrt(64)
constexpr float INV_SQRT_CA = 0.027950849718747374f;  // 1/sqrt(1280)
constexpr float INV_SQRT_2C = 0.0625f;                // 1/sqrt(256)
constexpr float INV_SQRT_3  = 0.57735026918962576f;

typedef short short8 __attribute__((ext_vector_type(8)));
typedef float f32x4 __attribute__((ext_vector_type(4)));

__device__ __forceinline__ float silu_f(float x) { return x / (1.0f + __expf(-x)); }

__device__ __forceinline__ void atomic_add_f32(float* p, float v) {
  __hip_atomic_fetch_add(p, v, __ATOMIC_RELAXED, __HIP_MEMORY_SCOPE_AGENT);
}

__device__ __forceinline__ unsigned short f2bf(float f) {
  unsigned int u = __builtin_bit_cast(unsigned int, f);
  u += 0x7fffu + ((u >> 16) & 1u);  // RNE
  return (unsigned short)(u >> 16);
}

// ---------------------------------------------------------------------------
// K1: H[n, u*4+0] = h0[n,u],  H[n, u*4+1+k] = h1[n,u,k]
// ---------------------------------------------------------------------------
__global__ __launch_bounds__(256) void k_node_up(
    const float* __restrict__ nf, const float* __restrict__ Wu0,
    const float* __restrict__ Wu1, float* __restrict__ H) {
  __shared__ __align__(16) float xs[8][C][4];
  const int t = threadIdx.x;
  const int n0 = blockIdx.x * 8;
  for (int idx = t; idx < 8 * 512; idx += 256) {
    const int nn = idx >> 9, q = idx & 511;
    const float val = nf[(size_t)(n0 + nn) * 512 + q];
    if (q < C) xs[nn][q][0] = val;
    else { const int r = q - C; xs[nn][r / 3][1 + r % 3] = val; }
  }
  __syncthreads();
  const int g = t >> 7, v = t & 127;
  float acc[4][4] = {};
  for (int u = 0; u < C; ++u) {
    const float w0 = Wu0[u * C + v];
    const float w1 = Wu1[u * C + v];
#pragma unroll
    for (int nn = 0; nn < 4; ++nn) {
      const float4 xv = *(const float4*)&xs[g * 4 + nn][u][0];
      acc[nn][0] = fmaf(xv.x, w0, acc[nn][0]);
      acc[nn][1] = fmaf(xv.y, w1, acc[nn][1]);
      acc[nn][2] = fmaf(xv.z, w1, acc[nn][2]);
      acc[nn][3] = fmaf(xv.w, w1, acc[nn][3]);
    }
  }
#pragma unroll
  for (int nn = 0; nn < 4; ++nn) {
    const int n = n0 + g * 4 + nn;
    float4 o;
    o.x = acc[nn][0] * INV_SQRT_C; o.y = acc[nn][1] * INV_SQRT_C;
    o.z = acc[nn][2] * INV_SQRT_C; o.w = acc[nn][3] * INV_SQRT_C;
    *(float4*)&H[(size_t)n * 512 + v * 4] = o;
  }
}

// ---------------------------------------------------------------------------
// k_cvt: pre-convert + fragment-swizzle Ws0/Ws1 (fp32 [u][a][v], i.e. row-major
// 1280x128 with K-index k=u*10+a) into Bsw[kt][col][kk] bf16, kt=k>>5, kk=k&31.
// Lane B-fragment for 16x16x32 MFMA then reads 8 contiguous bf16 (16 B).
// ---------------------------------------------------------------------------
__global__ __launch_bounds__(256) void k_cvt(
    const float* __restrict__ W0, const float* __restrict__ W1,
    unsigned short* __restrict__ B0, unsigned short* __restrict__ B1) {
  const int idx = blockIdx.x * 256 + threadIdx.x;
  if (idx < 1280 * 128) {
    const int k = idx >> 7, col = idx & 127;
    const int dst = ((k >> 5) * 128 + col) * 32 + (k & 31);
    B0[dst] = f2bf(W0[idx]);
    B1[dst] = f2bf(W1[idx]);
  }
}

// ---------------------------------------------------------------------------
// K2 (MFMA): sc as two bf16 GEMMs with on-the-fly Z-tile formation.
//   G0 (blocks 0..156):    rows r=n (10000),   Z0[r,k]=x0[n,u]*attr[n,a], B=Bsw0
//   G1 (blocks 157..625):  rows r=n*3+k (30000), Z1[r,k]=x1[n,u,kc]*attr[n,a], B=Bsw1
// Block tile 64 rows x 128 cols, K=1280 (40 iters of 32). 4 waves: wave w owns
// cols [w*32, w*32+32). Z tile in LDS bf16 [64][40] (pad for even bank use).
// ---------------------------------------------------------------------------
__global__ __launch_bounds__(256) void k_skip_mfma(
    const float* __restrict__ nf, const float* __restrict__ attrs,
    const unsigned short* __restrict__ B0, const unsigned short* __restrict__ B1,
    float* __restrict__ out_sc) {
  __shared__ __align__(16) float xs[64][128];      // 32 KB
  __shared__ float at[64][10];                     // 2.5 KB
  __shared__ __align__(16) unsigned short zs[64][40];  // 5 KB

  const int t = threadIdx.x;
  const int wave = t >> 6, lane = t & 63;
  const bool isG0 = blockIdx.x < 157;
  const int r0 = isG0 ? blockIdx.x * 64 : (blockIdx.x - 157) * 64;
  const int rcount = isG0 ? 10000 : 30000;
  const unsigned short* __restrict__ Bsw = isG0 ? B0 : B1;

  // stage x and attr for this block's 64 rows
  for (int idx = t; idx < 64 * 128; idx += 256) {
    const int i = idx >> 7, u = idx & 127;
    const int r = r0 + i;
    float v = 0.f;
    if (r < rcount) {
      if (isG0) v = nf[(size_t)r * 512 + u];
      else {
        const int n = r / 3, kc = r - n * 3;
        v = nf[(size_t)n * 512 + 128 + u * 3 + kc];
      }
    }
    xs[i][u] = v;
  }
  for (int idx = t; idx < 640; idx += 256) {
    const int i = idx / 10, a = idx - (idx / 10) * 10;
    const int r = r0 + i;
    float v = 0.f;
    if (r < rcount) v = attrs[(size_t)(isG0 ? r : r / 3) * 10 + a];
    at[i][a] = v;
  }
  __syncthreads();

  const int m = lane & 15, q = lane >> 4;
  const int colB = wave * 32;

  f32x4 acc[4][2];
#pragma unroll
  for (int rt = 0; rt < 4; ++rt)
#pragma unroll
    for (int ct = 0; ct < 2; ++ct) acc[rt][ct] = (f32x4){0.f, 0.f, 0.f, 0.f};

  for (int kt = 0; kt < 40; ++kt) {
    // Z-tile formation: thread -> row t>>2, kk block (t&3)*8..+7
    {
      const int r = t >> 2;
      const int kkb = (t & 3) * 8;
      const int kbase = kt * 32 + kkb;
      unsigned int pk[4];
#pragma unroll
      for (int j = 0; j < 4; ++j) {
        const int k0 = kbase + 2 * j;
        const int u0 = k0 / 10, a0 = k0 - u0 * 10;
        const int k1 = k0 + 1;
        const int u1 = k1 / 10, a1 = k1 - u1 * 10;
        const unsigned short lo = f2bf(xs[r][u0] * at[r][a0]);
        const unsigned short hi = f2bf(xs[r][u1] * at[r][a1]);
        pk[j] = (unsigned int)lo | ((unsigned int)hi << 16);
      }
      *(uint4*)&zs[r][kkb] = make_uint4(pk[0], pk[1], pk[2], pk[3]);
    }
    __syncthreads();

    // B fragments straight from L2 (pre-swizzled): 16 B per lane per col-tile
    short8 bfrag[2];
#pragma unroll
    for (int ct = 0; ct < 2; ++ct) {
      const unsigned short* bp =
          &Bsw[(size_t)(kt * 128 + colB + ct * 16 + m) * 32 + q * 8];
      bfrag[ct] = *(const short8*)bp;
    }
    // A fragments from LDS + MFMA
#pragma unroll
    for (int rt = 0; rt < 4; ++rt) {
      const short8 afrag = *(const short8*)&zs[rt * 16 + m][q * 8];
#pragma unroll
      for (int ct = 0; ct < 2; ++ct)
        acc[rt][ct] = __builtin_amdgcn_mfma_f32_16x16x32_bf16(
            afrag, bfrag[ct], acc[rt][ct], 0, 0, 0);
    }
    __syncthreads();
  }

  // Epilogue: C/D layout col=lane&15, row=(lane>>4)*4+reg
#pragma unroll
  for (int rt = 0; rt < 4; ++rt) {
#pragma unroll
    for (int reg = 0; reg < 4; ++reg) {
      const int rloc = rt * 16 + q * 4 + reg;
      const int r = r0 + rloc;
      if (r < rcount) {
#pragma unroll
        for (int ct = 0; ct < 2; ++ct) {
          const int v = colB + ct * 16 + m;
          const float val = acc[rt][ct][reg] * INV_SQRT_CA;
          if (isG0) {
            out_sc[(size_t)r * 512 + v] = val;
          } else {
            const int n = r / 3, kc = r - (r / 3) * 3;
            out_sc[(size_t)n * 512 + 128 + v * 3 + kc] = val;
          }
        }
      }
    }
  }
}

// ---------------------------------------------------------------------------
// Sort-by-receiver: histogram -> scan -> scatter (fills sorted aux arrays)
// ---------------------------------------------------------------------------
__global__ __launch_bounds__(256) void k_hist(const int* __restrict__ eidx,
                                              int* __restrict__ counts) {
  const int e = blockIdx.x * 256 + threadIdx.x;
  if (e < N_EDGES) atomicAdd(&counts[eidx[N_EDGES + e]], 1);
}

__global__ __launch_bounds__(1024) void k_scan(const int* __restrict__ counts,
                                               int* __restrict__ offsets,
                                               int* __restrict__ cursor) {
  __shared__ int part[1024];
  const int t = threadIdx.x;
  int local[10];
  int s = 0;
#pragma unroll
  for (int i = 0; i < 10; ++i) {
    const int idx = t * 10 + i;
    const int c = (idx < N_NODES) ? counts[idx] : 0;
    local[i] = s;
    s += c;
  }
  part[t] = s;
  __syncthreads();
  for (int off = 1; off < 1024; off <<= 1) {
    const int add = (t >= off) ? part[t - off] : 0;
    __syncthreads();
    part[t] += add;
    __syncthreads();
  }
  const int pre = (t > 0) ? part[t - 1] : 0;
#pragma unroll
  for (int i = 0; i < 10; ++i) {
    const int idx = t * 10 + i;
    if (idx < N_NODES) {
      const int o = pre + local[i];
      offsets[idx] = o;
      cursor[idx] = o;
    }
  }
  if (t == 1023) offsets[N_NODES] = part[1023];
}

__global__ __launch_bounds__(256) void k_scatter(
    const int* __restrict__ eidx, const float* __restrict__ ea_g,
    int* __restrict__ cursor, int* __restrict__ perm,
    int* __restrict__ snd_s, int* __restrict__ rcv_s,
    float* __restrict__ ea_s) {
  const int e = blockIdx.x * 256 + threadIdx.x;
  if (e < N_EDGES) {
    const int r = eidx[N_EDGES + e];
    const int pos = atomicAdd(&cursor[r], 1);
    perm[pos] = e;
    snd_s[pos] = eidx[e];
    rcv_s[pos] = r;
    ((float4*)ea_s)[pos] = ((const float4*)ea_g)[e];
  }
}

// ---------------------------------------------------------------------------
// K3: edge MLP (8->64->64->64->512), edges in SORTED order, W output as fp16.
// ---------------------------------------------------------------------------
__global__ __launch_bounds__(256) void k_mlp(
    const int* __restrict__ perm, const int* __restrict__ rcv_s,
    const float* __restrict__ ef_g,
    const float* __restrict__ R0, const float* __restrict__ R1,
    const float* __restrict__ R2, const float* __restrict__ R3,
    const float* __restrict__ Wd,
    __half* __restrict__ W, float* __restrict__ density) {
  __shared__ __align__(16) float efs[16][8];
  __shared__ __align__(16) float b0[16][64];
  __shared__ __align__(16) float b1[16][64];
  __shared__ int es[16];
  const int t = threadIdx.x;
  const int e0 = blockIdx.x * 16;

  if (t < 16) es[t] = perm[e0 + t];
  __syncthreads();
  if (t < 128) efs[t >> 3][t & 7] = ef_g[(size_t)es[t >> 3] * 8 + (t & 7)];
  __syncthreads();

  if (t < 16) {
    float s = 0.f;
#pragma unroll
    for (int i = 0; i < 8; ++i) s = fmaf(efs[t][i], Wd[i], s);
    s *= INV_SQRT_R;
    atomic_add_f32(&density[rcv_s[e0 + t]], tanhf(s * s));
  }

  // L1: 8 -> 64
  {
    const int j = t & 63;
#pragma unroll
    for (int r = 0; r < 4; ++r) {
      const int e = (t >> 6) + r * 4;
      float s = 0.f;
#pragma unroll
      for (int i = 0; i < 8; ++i) s = fmaf(efs[e][i], R0[i * 64 + j], s);
      b0[e][j] = silu_f(s * INV_SQRT_R);
    }
  }
  __syncthreads();

  // L2: 64 -> 64 (b0 -> b1)
  {
    const int e = t >> 4, jg = t & 15;
    float a2[4] = {};
    for (int i0 = 0; i0 < 64; i0 += 4) {
      const float4 b = *(const float4*)&b0[e][i0];
#pragma unroll
      for (int ii = 0; ii < 4; ++ii) {
        const float bv = (&b.x)[ii];
#pragma unroll
        for (int qq = 0; qq < 4; ++qq)
          a2[qq] = fmaf(bv, R1[(i0 + ii) * 64 + jg + 16 * qq], a2[qq]);
      }
    }
#pragma unroll
    for (int qq = 0; qq < 4; ++qq) b1[e][jg + 16 * qq] = silu_f(a2[qq] * INV_SQRT_64);
  }
  __syncthreads();

  // L3: 64 -> 64 (b1 -> b0)
  {
    const int e = t >> 4, jg = t & 15;
    float a3[4] = {};
    for (int i0 = 0; i0 < 64; i0 += 4) {
      const float4 b = *(const float4*)&b1[e][i0];
#pragma unroll
      for (int ii = 0; ii < 4; ++ii) {
        const float bv = (&b.x)[ii];
#pragma unroll
        for (int qq = 0; qq < 4; ++qq)
          a3[qq] = fmaf(bv, R2[(i0 + ii) * 64 + jg + 16 * qq], a3[qq]);
      }
    }
    __syncthreads();
#pragma unroll
    for (int qq = 0; qq < 4; ++qq) b0[e][jg + 16 * qq] = silu_f(a3[qq] * INV_SQRT_64);
  }
  __syncthreads();

  // L4: 64 -> 512, write fp16 to global W (sorted edge order)
  {
    const int eg = t >> 7;
    const int jg = t & 127;
    float wacc[8][4] = {};
    for (int i0 = 0; i0 < 64; i0 += 4) {
      float4 bb[8];
#pragma unroll
      for (int e = 0; e < 8; ++e) bb[e] = *(const float4*)&b0[eg * 8 + e][i0];
#pragma unroll
      for (int ii = 0; ii < 4; ++ii) {
        const float4 r4 = *(const float4*)&R3[(size_t)(i0 + ii) * 512 + jg * 4];
#pragma unroll
        for (int e = 0; e < 8; ++e) {
          const float bv = (&bb[e].x)[ii];
          wacc[e][0] = fmaf(bv, r4.x, wacc[e][0]);
          wacc[e][1] = fmaf(bv, r4.y, wacc[e][1]);
          wacc[e][2] = fmaf(bv, r4.z, wacc[e][2]);
          wacc[e][3] = fmaf(bv, r4.w, wacc[e][3]);
        }
      }
    }
#pragma unroll
    for (int e = 0; e < 8; ++e) {
      __half2 lo = __floats2half2_rn(wacc[e][0] * INV_SQRT_64, wacc[e][1] * INV_SQRT_64);
      __half2 hi = __floats2half2_rn(wacc[e][2] * INV_SQRT_64, wacc[e][3] * INV_SQRT_64);
      uint2 pk;
      pk.x = *(unsigned int*)&lo;
      pk.y = *(unsigned int*)&hi;
      *(uint2*)&W[(size_t)(e0 + eg * 8 + e) * 512 + jg * 4] = pk;
    }
  }
}

// ---------------------------------------------------------------------------
// K4: message formation + segmented reduction over sorted edges.
// ---------------------------------------------------------------------------
__global__ __launch_bounds__(256) void k_message(
    const int* __restrict__ snd_s, const int* __restrict__ rcv_s,
    const int* __restrict__ offsets, const float* __restrict__ ea_s,
    const __half* __restrict__ W, const float* __restrict__ H,
    float* __restrict__ M) {
  __shared__ int sn[64], rc[64];
  __shared__ __align__(16) float ys[64][4];
  const int t = threadIdx.x;
  const int base = blockIdx.x * 64;
  if (t < 64) { sn[t] = snd_s[base + t]; rc[t] = rcv_s[base + t]; }
  ys[t >> 2][t & 3] = ea_s[(size_t)base * 4 + t];
  __syncthreads();

  const int u = t & 127, half = t >> 7;
  float a0 = 0.f, a1 = 0.f, a2 = 0.f, a3 = 0.f;
  int cur = rc[0];

  auto flush = [&](int n) {
    const int s0 = offsets[n], s1 = offsets[n + 1];
    float* Mp = &M[(size_t)n * 1024 + (half << 9) + (u << 2)];
    if (s0 >= base && s1 <= base + 64) {
      *(float4*)Mp = make_float4(a0, a1, a2, a3);
    } else {
      atomic_add_f32(Mp + 0, a0);
      atomic_add_f32(Mp + 1, a1);
      atomic_add_f32(Mp + 2, a2);
      atomic_add_f32(Mp + 3, a3);
    }
  };

  for (int e = 0; e < 64; ++e) {
    const int n = rc[e];
    if (n != cur) {
      flush(cur);
      a0 = a1 = a2 = a3 = 0.f;
      cur = n;
    }
    const int s = sn[e];
    const float4 h4 = *(const float4*)&H[(size_t)s * 512 + (u << 2)];
    const float y0 = ys[e][0];
    const float y1x = ys[e][1], y1y = ys[e][2], y1z = ys[e][3];
    const size_t wb = (size_t)(base + e) * 512;
    if (half == 0) {
      const float w1v = __half2float(W[wb + u]);
      const float w2v = __half2float(W[wb + 128 + u]);
      a0 = fmaf(w1v * h4.x, y0, a0);
      const float c1 = w2v * h4.x;
      a1 = fmaf(c1, y1x, a1);
      a2 = fmaf(c1, y1y, a2);
      a3 = fmaf(c1, y1z, a3);
    } else {
      const float w3v = __half2float(W[wb + 256 + u]);
      const float w4v = __half2float(W[wb + 384 + u]);
      const float dt = h4.y * y1x + h4.z * y1y + h4.w * y1z;
      a0 = fmaf(w4v * dt, INV_SQRT_3, a0);
      const float c3 = w3v * y0;
      a1 = fmaf(c3, h4.y, a1);
      a2 = fmaf(c3, h4.z, a2);
      a3 = fmaf(c3, h4.w, a3);
    }
  }
  flush(cur);
}

// ---------------------------------------------------------------------------
// K5: out0 = M0 @ Wl0 /16/denom; out1[.,.,k] = M1[...,k] @ Wl1 /16/denom
// ---------------------------------------------------------------------------
__global__ __launch_bounds__(256) void k_out(
    const float* __restrict__ M, const float* __restrict__ density,
    const float* __restrict__ Wl0, const float* __restrict__ Wl1,
    float* __restrict__ out) {
  __shared__ __align__(16) float Ms[8][256][4];  // 32 KB
  __shared__ float dens[8];
  const int t = threadIdx.x;
  const int n0 = blockIdx.x * 8;
  const float4* Msrc = (const float4*)&M[(size_t)n0 * 1024];
  float4* Mdst = (float4*)&Ms[0][0][0];
  for (int idx = t; idx < 8 * 256; idx += 256) Mdst[idx] = Msrc[idx];
  if (t < 8) dens[t] = density[n0 + t] + 1.0f;
  __syncthreads();
  const int g = t >> 7, v = t & 127;
  float acc[4][4] = {};
  for (int p0 = 0; p0 < 256; p0 += 4) {
    float4 mv[4][4];
#pragma unroll
    for (int nn = 0; nn < 4; ++nn)
#pragma unroll
      for (int j = 0; j < 4; ++j)
        mv[nn][j] = *(const float4*)&Ms[g * 4 + nn][p0 + j][0];
#pragma unroll
    for (int j = 0; j < 4; ++j) {
      const float w0 = Wl0[(p0 + j) * C + v];
      const float w1 = Wl1[(p0 + j) * C + v];
#pragma unroll
      for (int nn = 0; nn < 4; ++nn) {
        acc[nn][0] = fmaf(mv[nn][j].x, w0, acc[nn][0]);
        acc[nn][1] = fmaf(mv[nn][j].y, w1, acc[nn][1]);
        acc[nn][2] = fmaf(mv[nn][j].z, w1, acc[nn][2]);
        acc[nn][3] = fmaf(mv[nn][j].w, w1, acc[nn][3]);
      }
    }
  }
#pragma unroll
  for (int nn = 0; nn < 4; ++nn) {
    const int n = n0 + g * 4 + nn;
    const float sc = INV_SQRT_2C / dens[g * 4 + nn];
    float4 o;
    o.x = acc[nn][0] * sc; o.y = acc[nn][1] * sc;
    o.z = acc[nn][2] * sc; o.w = acc[nn][3] * sc;
    *(float4*)&out[(size_t)n * 512 + v * 4] = o;
  }
}

// ---------------------------------------------------------------------------
extern "C" void kernel_launch(void* const* d_in, const int* in_sizes, int n_in,
                              void* d_out, int out_size, void* d_ws, size_t ws_size,
                              hipStream_t stream) {
  const float* node_attrs = (const float*)d_in[0];
  const float* node_feats = (const float*)d_in[1];
  const float* edge_attrs = (const float*)d_in[2];
  const float* edge_feats = (const float*)d_in[3];
  const int*   edge_index = (const int*)d_in[4];
  const float* W_up0 = (const float*)d_in[5];
  const float* W_up1 = (const float*)d_in[6];
  const float* R0 = (const float*)d_in[7];
  const float* R1 = (const float*)d_in[8];
  const float* R2 = (const float*)d_in[9];
  const float* R3 = (const float*)d_in[10];
  const float* Wd  = (const float*)d_in[11];
  const float* Wl0 = (const float*)d_in[12];
  const float* Wl1 = (const float*)d_in[13];
  const float* Ws0 = (const float*)d_in[14];
  const float* Ws1 = (const float*)d_in[15];
  float* out = (float*)d_out;

  // Workspace layout:
  // H (N*512 f32) | M (N*1024 f32) | density (N) | counts | offsets | cursor |
  // perm | snd_s | rcv_s (E ints) | ea_s (E*4 f32) | W (E*512 half) |
  // Bsw0 | Bsw1 (1280*128 ushort each)
  float* H = (float*)d_ws;
  float* M = H + (size_t)N_NODES * 512;
  float* density = M + (size_t)N_NODES * 1024;
  int* counts  = (int*)(density + 10000);
  int* offsets = counts + 10016;
  int* cursor  = offsets + 10016;
  int* perm    = cursor + 10016;
  int* snd_s   = perm + N_EDGES;
  int* rcv_s   = snd_s + N_EDGES;
  float* ea_s  = (float*)(rcv_s + N_EDGES);
  __half* W    = (__half*)(ea_s + (size_t)N_EDGES * 4);
  unsigned short* Bsw0 = (unsigned short*)(W + (size_t)N_EDGES * 512);
  unsigned short* Bsw1 = Bsw0 + 1280 * 128;

  // zero M + density + counts (contiguous)
  hipMemsetAsync(M, 0, ((size_t)N_NODES * 1024 + 10000 + 10016) * sizeof(float),
                 stream);

  k_node_up<<<N_NODES / 8, 256, 0, stream>>>(node_feats, W_up0, W_up1, H);
  k_cvt<<<640, 256, 0, stream>>>(Ws0, Ws1, Bsw0, Bsw1);
  k_hist<<<(N_EDGES + 255) / 256, 256, 0, stream>>>(edge_index, counts);
  k_scan<<<1, 1024, 0, stream>>>(counts, offsets, cursor);
  k_scatter<<<(N_EDGES + 255) / 256, 256, 0, stream>>>(edge_index, edge_attrs,
                                                       cursor, perm, snd_s,
                                                       rcv_s, ea_s);
  k_mlp<<<N_EDGES / 16, 256, 0, stream>>>(perm, rcv_s, edge_feats, R0, R1, R2,
                                          R3, Wd, W, density);
  k_message<<<N_EDGES / 64, 256, 0, stream>>>(snd_s, rcv_s, offsets, ea_s, W, H,
                                              M);
  k_out<<<N_NODES / 8, 256, 0, stream>>>(M, density, Wl0, Wl1, out);
  k_skip_mfma<<<157 + 469, 256, 0, stream>>>(node_feats, node_attrs, Bsw0, Bsw1,
                                             out + (size_t)N_NODES * 512);
}

// Round 6
// 455.743 us; speedup vs baseline: 6.0257x; 1.3939x over previous
//
#include <hip/hip_runtime.h>
#include <hip/hip_bf16.h>
#include <hip/hip_fp16.h>

// Problem constants
#define N_NODES 10000
#define N_EDGES 128000
constexpr int C = 128;
constexpr int A = 10;

constexpr float INV_SQRT_C  = 0.08838834764831845f;   // 1/sqrt(128)
constexpr float INV_SQRT_R  = 0.35355339059327373f;   // 1/sqrt(8)
constexpr float INV_SQRT_64 = 0.125f;                 // 1/sqrt(64)
constexpr float INV_SQRT_CA = 0.027950849718747374f;  // 1/sqrt(1280)
constexpr float INV_SQRT_2C = 0.0625f;                // 1/sqrt(256)
constexpr float INV_SQRT_3  = 0.57735026918962576f;

typedef short short8 __attribute__((ext_vector_type(8)));
typedef _Float16 f16x8 __attribute__((ext_vector_type(8)));
typedef float f32x4 __attribute__((ext_vector_type(4)));

__device__ __forceinline__ float silu_f(float x) { return x / (1.0f + __expf(-x)); }

__device__ __forceinline__ void atomic_add_f32(float* p, float v) {
  __hip_atomic_fetch_add(p, v, __ATOMIC_RELAXED, __HIP_MEMORY_SCOPE_AGENT);
}

__device__ __forceinline__ unsigned short f2bf(float f) {
  unsigned int u = __builtin_bit_cast(unsigned int, f);
  u += 0x7fffu + ((u >> 16) & 1u);  // RNE
  return (unsigned short)(u >> 16);
}

__device__ __forceinline__ unsigned int pk2h(float a, float b) {
  auto h = __builtin_amdgcn_cvt_pkrtz(a, b);  // __fp16 ext_vector(2)
  return __builtin_bit_cast(unsigned int, h);
}

// ---------------------------------------------------------------------------
// K1: H[n, u*4+0] = h0[n,u],  H[n, u*4+1+k] = h1[n,u,k]
// ---------------------------------------------------------------------------
__global__ __launch_bounds__(256) void k_node_up(
    const float* __restrict__ nf, const float* __restrict__ Wu0,
    const float* __restrict__ Wu1, float* __restrict__ H) {
  __shared__ __align__(16) float xs[8][C][4];
  const int t = threadIdx.x;
  const int n0 = blockIdx.x * 8;
  for (int idx = t; idx < 8 * 512; idx += 256) {
    const int nn = idx >> 9, q = idx & 511;
    const float val = nf[(size_t)(n0 + nn) * 512 + q];
    if (q < C) xs[nn][q][0] = val;
    else { const int r = q - C; xs[nn][r / 3][1 + r % 3] = val; }
  }
  __syncthreads();
  const int g = t >> 7, v = t & 127;
  float acc[4][4] = {};
  for (int u = 0; u < C; ++u) {
    const float w0 = Wu0[u * C + v];
    const float w1 = Wu1[u * C + v];
#pragma unroll
    for (int nn = 0; nn < 4; ++nn) {
      const float4 xv = *(const float4*)&xs[g * 4 + nn][u][0];
      acc[nn][0] = fmaf(xv.x, w0, acc[nn][0]);
      acc[nn][1] = fmaf(xv.y, w1, acc[nn][1]);
      acc[nn][2] = fmaf(xv.z, w1, acc[nn][2]);
      acc[nn][3] = fmaf(xv.w, w1, acc[nn][3]);
    }
  }
#pragma unroll
  for (int nn = 0; nn < 4; ++nn) {
    const int n = n0 + g * 4 + nn;
    float4 o;
    o.x = acc[nn][0] * INV_SQRT_C; o.y = acc[nn][1] * INV_SQRT_C;
    o.z = acc[nn][2] * INV_SQRT_C; o.w = acc[nn][3] * INV_SQRT_C;
    *(float4*)&H[(size_t)n * 512 + v * 4] = o;
  }
}

// ---------------------------------------------------------------------------
// k_cvt: pre-convert + B-fragment-swizzle Ws0/Ws1 into bf16 (skip GEMM).
// ---------------------------------------------------------------------------
__global__ __launch_bounds__(256) void k_cvt(
    const float* __restrict__ W0, const float* __restrict__ W1,
    unsigned short* __restrict__ B0, unsigned short* __restrict__ B1) {
  const int idx = blockIdx.x * 256 + threadIdx.x;
  if (idx < 1280 * 128) {
    const int k = idx >> 7, col = idx & 127;
    const int dst = ((k >> 5) * 128 + col) * 32 + (k & 31);
    B0[dst] = f2bf(W0[idx]);
    B1[dst] = f2bf(W1[idx]);
  }
}

// ---------------------------------------------------------------------------
// k_cvt_w: weight (K x N fp32, row-major) -> f16 A-operand swizzle of W^T:
// dst[((n*(K/32) + kt)*32 + kk)] = f16(src[(kt*32+kk)*N + n]).
// ---------------------------------------------------------------------------
__global__ __launch_bounds__(256) void k_cvt_w(
    const float* __restrict__ src, unsigned short* __restrict__ dst,
    int total, int lgN, int KT) {
  const int idx = blockIdx.x * 256 + threadIdx.x;
  if (idx < total) {
    const int k = idx >> lgN;
    const int n = idx & ((1 << lgN) - 1);
    const _Float16 h = (_Float16)src[idx];
    dst[((n * KT + (k >> 5)) << 5) + (k & 31)] =
        __builtin_bit_cast(unsigned short, h);
  }
}

// ---------------------------------------------------------------------------
// K2 (MFMA): sc as two bf16 GEMMs with on-the-fly Z-tile formation.
// ---------------------------------------------------------------------------
__global__ __launch_bounds__(256) void k_skip_mfma(
    const float* __restrict__ nf, const float* __restrict__ attrs,
    const unsigned short* __restrict__ B0, const unsigned short* __restrict__ B1,
    float* __restrict__ out_sc) {
  __shared__ __align__(16) float xs[64][128];      // 32 KB
  __shared__ float at[64][10];                     // 2.5 KB
  __shared__ __align__(16) unsigned short zs[64][40];  // 5 KB

  const int t = threadIdx.x;
  const int wave = t >> 6, lane = t & 63;
  const bool isG0 = blockIdx.x < 157;
  const int r0 = isG0 ? blockIdx.x * 64 : (blockIdx.x - 157) * 64;
  const int rcount = isG0 ? 10000 : 30000;
  const unsigned short* __restrict__ Bsw = isG0 ? B0 : B1;

  for (int idx = t; idx < 64 * 128; idx += 256) {
    const int i = idx >> 7, u = idx & 127;
    const int r = r0 + i;
    float v = 0.f;
    if (r < rcount) {
      if (isG0) v = nf[(size_t)r * 512 + u];
      else {
        const int n = r / 3, kc = r - n * 3;
        v = nf[(size_t)n * 512 + 128 + u * 3 + kc];
      }
    }
    xs[i][u] = v;
  }
  for (int idx = t; idx < 640; idx += 256) {
    const int i = idx / 10, a = idx - (idx / 10) * 10;
    const int r = r0 + i;
    float v = 0.f;
    if (r < rcount) v = attrs[(size_t)(isG0 ? r : r / 3) * 10 + a];
    at[i][a] = v;
  }
  __syncthreads();

  const int m = lane & 15, q = lane >> 4;
  const int colB = wave * 32;

  f32x4 acc[4][2];
#pragma unroll
  for (int rt = 0; rt < 4; ++rt)
#pragma unroll
    for (int ct = 0; ct < 2; ++ct) acc[rt][ct] = (f32x4){0.f, 0.f, 0.f, 0.f};

  for (int kt = 0; kt < 40; ++kt) {
    {
      const int r = t >> 2;
      const int kkb = (t & 3) * 8;
      const int kbase = kt * 32 + kkb;
      unsigned int pk[4];
#pragma unroll
      for (int j = 0; j < 4; ++j) {
        const int k0 = kbase + 2 * j;
        const int u0 = k0 / 10, a0 = k0 - u0 * 10;
        const int k1 = k0 + 1;
        const int u1 = k1 / 10, a1 = k1 - u1 * 10;
        const unsigned short lo = f2bf(xs[r][u0] * at[r][a0]);
        const unsigned short hi = f2bf(xs[r][u1] * at[r][a1]);
        pk[j] = (unsigned int)lo | ((unsigned int)hi << 16);
      }
      *(uint4*)&zs[r][kkb] = make_uint4(pk[0], pk[1], pk[2], pk[3]);
    }
    __syncthreads();

    short8 bfrag[2];
#pragma unroll
    for (int ct = 0; ct < 2; ++ct) {
      const unsigned short* bp =
          &Bsw[(size_t)(kt * 128 + colB + ct * 16 + m) * 32 + q * 8];
      bfrag[ct] = *(const short8*)bp;
    }
#pragma unroll
    for (int rt = 0; rt < 4; ++rt) {
      const short8 afrag = *(const short8*)&zs[rt * 16 + m][q * 8];
#pragma unroll
      for (int ct = 0; ct < 2; ++ct)
        acc[rt][ct] = __builtin_amdgcn_mfma_f32_16x16x32_bf16(
            afrag, bfrag[ct], acc[rt][ct], 0, 0, 0);
    }
    __syncthreads();
  }

#pragma unroll
  for (int rt = 0; rt < 4; ++rt) {
#pragma unroll
    for (int reg = 0; reg < 4; ++reg) {
      const int rloc = rt * 16 + q * 4 + reg;
      const int r = r0 + rloc;
      if (r < rcount) {
#pragma unroll
        for (int ct = 0; ct < 2; ++ct) {
          const int v = colB + ct * 16 + m;
          const float val = acc[rt][ct][reg] * INV_SQRT_CA;
          if (isG0) {
            out_sc[(size_t)r * 512 + v] = val;
          } else {
            const int n = r / 3, kc = r - (r / 3) * 3;
            out_sc[(size_t)n * 512 + 128 + v * 3 + kc] = val;
          }
        }
      }
    }
  }
}

// ---------------------------------------------------------------------------
// Sort-by-receiver: histogram -> scan -> scatter (fills sorted aux arrays)
// ---------------------------------------------------------------------------
__global__ __launch_bounds__(256) void k_hist(const int* __restrict__ eidx,
                                              int* __restrict__ counts) {
  const int e = blockIdx.x * 256 + threadIdx.x;
  if (e < N_EDGES) atomicAdd(&counts[eidx[N_EDGES + e]], 1);
}

__global__ __launch_bounds__(1024) void k_scan(const int* __restrict__ counts,
                                               int* __restrict__ offsets,
                                               int* __restrict__ cursor) {
  __shared__ int part[1024];
  const int t = threadIdx.x;
  int local[10];
  int s = 0;
#pragma unroll
  for (int i = 0; i < 10; ++i) {
    const int idx = t * 10 + i;
    const int c = (idx < N_NODES) ? counts[idx] : 0;
    local[i] = s;
    s += c;
  }
  part[t] = s;
  __syncthreads();
  for (int off = 1; off < 1024; off <<= 1) {
    const int add = (t >= off) ? part[t - off] : 0;
    __syncthreads();
    part[t] += add;
    __syncthreads();
  }
  const int pre = (t > 0) ? part[t - 1] : 0;
#pragma unroll
  for (int i = 0; i < 10; ++i) {
    const int idx = t * 10 + i;
    if (idx < N_NODES) {
      const int o = pre + local[i];
      offsets[idx] = o;
      cursor[idx] = o;
    }
  }
  if (t == 1023) offsets[N_NODES] = part[1023];
}

__global__ __launch_bounds__(256) void k_scatter(
    const int* __restrict__ eidx, const float* __restrict__ ea_g,
    const float* __restrict__ ef_g,
    int* __restrict__ cursor, int* __restrict__ perm,
    int* __restrict__ snd_s, int* __restrict__ rcv_s,
    float* __restrict__ ea_s, float* __restrict__ ef_s) {
  const int e = blockIdx.x * 256 + threadIdx.x;
  if (e < N_EDGES) {
    const int r = eidx[N_EDGES + e];
    const int pos = atomicAdd(&cursor[r], 1);
    perm[pos] = e;
    snd_s[pos] = eidx[e];
    rcv_s[pos] = r;
    ((float4*)ea_s)[pos] = ((const float4*)ea_g)[e];
    ((float4*)ef_s)[pos * 2]     = ((const float4*)ef_g)[e * 2];
    ((float4*)ef_s)[pos * 2 + 1] = ((const float4*)ef_g)[e * 2 + 1];
  }
}

// ---------------------------------------------------------------------------
// K3 (MFMA): edge MLP over 128 sorted edges/block.
// L1 (K=8) in VALU; L2/L3/L4 as f16 MFMA GEMMs computing C = W^T . act so the
// C layout (col=edge, row=4 consecutive channels) packs into 8-byte writes.
// Activations live in LDS f16 [128][72] (pad 64->72: 2-way bank alias = free).
// Weights pre-swizzled to A-operand layout (R1a/R2a/R3a, L2-resident).
// ---------------------------------------------------------------------------
__global__ __launch_bounds__(256) void k_mlp_mfma(
    const float* __restrict__ ef_s, const int* __restrict__ rcv_s,
    const float* __restrict__ R0, const unsigned short* __restrict__ R1a,
    const unsigned short* __restrict__ R2a, const unsigned short* __restrict__ R3a,
    const float* __restrict__ Wd,
    __half* __restrict__ W, float* __restrict__ density) {
  __shared__ __align__(16) float efs[128][9];            // 4.5 KB
  __shared__ __align__(16) unsigned short actA[128][72]; // 18 KB
  __shared__ __align__(16) unsigned short actB[128][72]; // 18 KB
  const int t = threadIdx.x;
  const int wave = t >> 6, lane = t & 63, m = lane & 15, q = lane >> 4;
  const int e0 = blockIdx.x * 128;

  // stage sorted edge feats: 256 threads x float4
  {
    const float4 v = *(const float4*)&ef_s[(size_t)e0 * 8 + t * 4];
    const int e = t >> 1, c0 = (t & 1) * 4;
    efs[e][c0] = v.x; efs[e][c0 + 1] = v.y;
    efs[e][c0 + 2] = v.z; efs[e][c0 + 3] = v.w;
  }
  __syncthreads();

  // density (one thread per edge)
  if (t < 128) {
    float s = 0.f;
#pragma unroll
    for (int i = 0; i < 8; ++i) s = fmaf(efs[t][i], Wd[i], s);
    s *= INV_SQRT_R;
    atomic_add_f32(&density[rcv_s[e0 + t]], tanhf(s * s));
  }

  // L1: 8 -> 64 (VALU), silu, f16 into actA. thread: edge t&127, j-half t>>7.
  {
    const int e = t & 127, j0 = (t >> 7) * 32;
    float a[32] = {};
#pragma unroll
    for (int i = 0; i < 8; ++i) {
      const float v = efs[e][i];
#pragma unroll
      for (int jj = 0; jj < 32; ++jj)
        a[jj] = fmaf(v, R0[i * 64 + j0 + jj], a[jj]);
    }
#pragma unroll
    for (int g = 0; g < 8; ++g) {
      uint2 pk;
      pk.x = pk2h(silu_f(a[4 * g] * INV_SQRT_R), silu_f(a[4 * g + 1] * INV_SQRT_R));
      pk.y = pk2h(silu_f(a[4 * g + 2] * INV_SQRT_R), silu_f(a[4 * g + 3] * INV_SQRT_R));
      *(uint2*)&actA[e][j0 + g * 4] = pk;
    }
  }
  __syncthreads();

  // L2: C = R1^T . actA -> silu -> actB. Wave w owns j-tile w (cols j w*16..).
  {
    const f16x8 af0 = *(const f16x8*)&R1a[(((wave * 16 + m) * 2 + 0) << 5) + q * 8];
    const f16x8 af1 = *(const f16x8*)&R1a[(((wave * 16 + m) * 2 + 1) << 5) + q * 8];
#pragma unroll
    for (int et = 0; et < 8; ++et) {
      const f16x8 bf0 = *(const f16x8*)&actA[et * 16 + m][q * 8];
      const f16x8 bf1 = *(const f16x8*)&actA[et * 16 + m][32 + q * 8];
      f32x4 c = {0.f, 0.f, 0.f, 0.f};
      c = __builtin_amdgcn_mfma_f32_16x16x32_f16(af0, bf0, c, 0, 0, 0);
      c = __builtin_amdgcn_mfma_f32_16x16x32_f16(af1, bf1, c, 0, 0, 0);
      uint2 pk;
      pk.x = pk2h(silu_f(c[0] * INV_SQRT_64), silu_f(c[1] * INV_SQRT_64));
      pk.y = pk2h(silu_f(c[2] * INV_SQRT_64), silu_f(c[3] * INV_SQRT_64));
      *(uint2*)&actB[et * 16 + m][wave * 16 + q * 4] = pk;
    }
  }
  __syncthreads();

  // L3: C = R2^T . actB -> silu -> actA
  {
    const f16x8 af0 = *(const f16x8*)&R2a[(((wave * 16 + m) * 2 + 0) << 5) + q * 8];
    const f16x8 af1 = *(const f16x8*)&R2a[(((wave * 16 + m) * 2 + 1) << 5) + q * 8];
#pragma unroll
    for (int et = 0; et < 8; ++et) {
      const f16x8 bf0 = *(const f16x8*)&actB[et * 16 + m][q * 8];
      const f16x8 bf1 = *(const f16x8*)&actB[et * 16 + m][32 + q * 8];
      f32x4 c = {0.f, 0.f, 0.f, 0.f};
      c = __builtin_amdgcn_mfma_f32_16x16x32_f16(af0, bf0, c, 0, 0, 0);
      c = __builtin_amdgcn_mfma_f32_16x16x32_f16(af1, bf1, c, 0, 0, 0);
      uint2 pk;
      pk.x = pk2h(silu_f(c[0] * INV_SQRT_64), silu_f(c[1] * INV_SQRT_64));
      pk.y = pk2h(silu_f(c[2] * INV_SQRT_64), silu_f(c[3] * INV_SQRT_64));
      *(uint2*)&actA[et * 16 + m][wave * 16 + q * 4] = pk;
    }
  }
  __syncthreads();

  // L4: C = R3^T . actA -> W (global, f16). Wave w owns j-tiles w*8..w*8+7.
  {
    f16x8 af[8][2];
#pragma unroll
    for (int jt = 0; jt < 8; ++jt)
#pragma unroll
      for (int kt = 0; kt < 2; ++kt)
        af[jt][kt] = *(const f16x8*)
            &R3a[((((wave * 8 + jt) * 16 + m) * 2 + kt) << 5) + q * 8];
#pragma unroll
    for (int et = 0; et < 8; ++et) {
      const f16x8 bf0 = *(const f16x8*)&actA[et * 16 + m][q * 8];
      const f16x8 bf1 = *(const f16x8*)&actA[et * 16 + m][32 + q * 8];
#pragma unroll
      for (int jt = 0; jt < 8; ++jt) {
        f32x4 c = {0.f, 0.f, 0.f, 0.f};
        c = __builtin_amdgcn_mfma_f32_16x16x32_f16(af[jt][0], bf0, c, 0, 0, 0);
        c = __builtin_amdgcn_mfma_f32_16x16x32_f16(af[jt][1], bf1, c, 0, 0, 0);
        uint2 pk;
        pk.x = pk2h(c[0] * INV_SQRT_64, c[1] * INV_SQRT_64);
        pk.y = pk2h(c[2] * INV_SQRT_64, c[3] * INV_SQRT_64);
        *(uint2*)&W[(size_t)(e0 + et * 16 + m) * 512 +
                    (wave * 8 + jt) * 16 + q * 4] = pk;
      }
    }
  }
}

// ---------------------------------------------------------------------------
// K4: message formation + segmented reduction over sorted edges.
// ---------------------------------------------------------------------------
__global__ __launch_bounds__(256) void k_message(
    const int* __restrict__ snd_s, const int* __restrict__ rcv_s,
    const int* __restrict__ offsets, const float* __restrict__ ea_s,
    const __half* __restrict__ W, const float* __restrict__ H,
    float* __restrict__ M) {
  __shared__ int sn[64], rc[64];
  __shared__ __align__(16) float ys[64][4];
  const int t = threadIdx.x;
  const int base = blockIdx.x * 64;
  if (t < 64) { sn[t] = snd_s[base + t]; rc[t] = rcv_s[base + t]; }
  ys[t >> 2][t & 3] = ea_s[(size_t)base * 4 + t];
  __syncthreads();

  const int u = t & 127, half = t >> 7;
  float a0 = 0.f, a1 = 0.f, a2 = 0.f, a3 = 0.f;
  int cur = rc[0];

  auto flush = [&](int n) {
    const int s0 = offsets[n], s1 = offsets[n + 1];
    float* Mp = &M[(size_t)n * 1024 + (half << 9) + (u << 2)];
    if (s0 >= base && s1 <= base + 64) {
      *(float4*)Mp = make_float4(a0, a1, a2, a3);
    } else {
      atomic_add_f32(Mp + 0, a0);
      atomic_add_f32(Mp + 1, a1);
      atomic_add_f32(Mp + 2, a2);
      atomic_add_f32(Mp + 3, a3);
    }
  };

  for (int e = 0; e < 64; ++e) {
    const int n = rc[e];
    if (n != cur) {
      flush(cur);
      a0 = a1 = a2 = a3 = 0.f;
      cur = n;
    }
    const int s = sn[e];
    const float4 h4 = *(const float4*)&H[(size_t)s * 512 + (u << 2)];
    const float y0 = ys[e][0];
    const float y1x = ys[e][1], y1y = ys[e][2], y1z = ys[e][3];
    const size_t wb = (size_t)(base + e) * 512;
    if (half == 0) {
      const float w1v = __half2float(W[wb + u]);
      const float w2v = __half2float(W[wb + 128 + u]);
      a0 = fmaf(w1v * h4.x, y0, a0);
      const float c1 = w2v * h4.x;
      a1 = fmaf(c1, y1x, a1);
      a2 = fmaf(c1, y1y, a2);
      a3 = fmaf(c1, y1z, a3);
    } else {
      const float w3v = __half2float(W[wb + 256 + u]);
      const float w4v = __half2float(W[wb + 384 + u]);
      const float dt = h4.y * y1x + h4.z * y1y + h4.w * y1z;
      a0 = fmaf(w4v * dt, INV_SQRT_3, a0);
      const float c3 = w3v * y0;
      a1 = fmaf(c3, h4.y, a1);
      a2 = fmaf(c3, h4.z, a2);
      a3 = fmaf(c3, h4.w, a3);
    }
  }
  flush(cur);
}

// ---------------------------------------------------------------------------
// K5: out0 = M0 @ Wl0 /16/denom; out1[.,.,k] = M1[...,k] @ Wl1 /16/denom
// ---------------------------------------------------------------------------
__global__ __launch_bounds__(256) void k_out(
    const float* __restrict__ M, const float* __restrict__ density,
    const float* __restrict__ Wl0, const float* __restrict__ Wl1,
    float* __restrict__ out) {
  __shared__ __align__(16) float Ms[8][256][4];  // 32 KB
  __shared__ float dens[8];
  const int t = threadIdx.x;
  const int n0 = blockIdx.x * 8;
  const float4* Msrc = (const float4*)&M[(size_t)n0 * 1024];
  float4* Mdst = (float4*)&Ms[0][0][0];
  for (int idx = t; idx < 8 * 256; idx += 256) Mdst[idx] = Msrc[idx];
  if (t < 8) dens[t] = density[n0 + t] + 1.0f;
  __syncthreads();
  const int g = t >> 7, v = t & 127;
  float acc[4][4] = {};
  for (int p0 = 0; p0 < 256; p0 += 4) {
    float4 mv[4][4];
#pragma unroll
    for (int nn = 0; nn < 4; ++nn)
#pragma unroll
      for (int j = 0; j < 4; ++j)
        mv[nn][j] = *(const float4*)&Ms[g * 4 + nn][p0 + j][0];
#pragma unroll
    for (int j = 0; j < 4; ++j) {
      const float w0 = Wl0[(p0 + j) * C + v];
      const float w1 = Wl1[(p0 + j) * C + v];
#pragma unroll
      for (int nn = 0; nn < 4; ++nn) {
        acc[nn][0] = fmaf(mv[nn][j].x, w0, acc[nn][0]);
        acc[nn][1] = fmaf(mv[nn][j].y, w1, acc[nn][1]);
        acc[nn][2] = fmaf(mv[nn][j].z, w1, acc[nn][2]);
        acc[nn][3] = fmaf(mv[nn][j].w, w1, acc[nn][3]);
      }
    }
  }
#pragma unroll
  for (int nn = 0; nn < 4; ++nn) {
    const int n = n0 + g * 4 + nn;
    const float sc = INV_SQRT_2C / dens[g * 4 + nn];
    float4 o;
    o.x = acc[nn][0] * sc; o.y = acc[nn][1] * sc;
    o.z = acc[nn][2] * sc; o.w = acc[nn][3] * sc;
    *(float4*)&out[(size_t)n * 512 + v * 4] = o;
  }
}

// ---------------------------------------------------------------------------
extern "C" void kernel_launch(void* const* d_in, const int* in_sizes, int n_in,
                              void* d_out, int out_size, void* d_ws, size_t ws_size,
                              hipStream_t stream) {
  const float* node_attrs = (const float*)d_in[0];
  const float* node_feats = (const float*)d_in[1];
  const float* edge_attrs = (const float*)d_in[2];
  const float* edge_feats = (const float*)d_in[3];
  const int*   edge_index = (const int*)d_in[4];
  const float* W_up0 = (const float*)d_in[5];
  const float* W_up1 = (const float*)d_in[6];
  const float* R0 = (const float*)d_in[7];
  const float* R1 = (const float*)d_in[8];
  const float* R2 = (const float*)d_in[9];
  const float* R3 = (const float*)d_in[10];
  const float* Wd  = (const float*)d_in[11];
  const float* Wl0 = (const float*)d_in[12];
  const float* Wl1 = (const float*)d_in[13];
  const float* Ws0 = (const float*)d_in[14];
  const float* Ws1 = (const float*)d_in[15];
  float* out = (float*)d_out;

  // Workspace layout:
  // H | M | density | counts | offsets | cursor | perm | snd_s | rcv_s |
  // ea_s | W (half) | Bsw0 | Bsw1 | R1a | R2a | R3a (ushort) | ef_s
  float* H = (float*)d_ws;
  float* M = H + (size_t)N_NODES * 512;
  float* density = M + (size_t)N_NODES * 1024;
  int* counts  = (int*)(density + 10000);
  int* offsets = counts + 10016;
  int* cursor  = offsets + 10016;
  int* perm    = cursor + 10016;
  int* snd_s   = perm + N_EDGES;
  int* rcv_s   = snd_s + N_EDGES;
  float* ea_s  = (float*)(rcv_s + N_EDGES);
  __half* W    = (__half*)(ea_s + (size_t)N_EDGES * 4);
  unsigned short* Bsw0 = (unsigned short*)(W + (size_t)N_EDGES * 512);
  unsigned short* Bsw1 = Bsw0 + 1280 * 128;
  unsigned short* R1a  = Bsw1 + 1280 * 128;
  unsigned short* R2a  = R1a + 64 * 64;
  unsigned short* R3a  = R2a + 64 * 64;
  float* ef_s  = (float*)(R3a + 64 * 512);

  // zero M + density + counts (contiguous)
  hipMemsetAsync(M, 0, ((size_t)N_NODES * 1024 + 10000 + 10016) * sizeof(float),
                 stream);

  k_node_up<<<N_NODES / 8, 256, 0, stream>>>(node_feats, W_up0, W_up1, H);
  k_cvt<<<640, 256, 0, stream>>>(Ws0, Ws1, Bsw0, Bsw1);
  k_cvt_w<<<16, 256, 0, stream>>>(R1, R1a, 64 * 64, 6, 2);
  k_cvt_w<<<16, 256, 0, stream>>>(R2, R2a, 64 * 64, 6, 2);
  k_cvt_w<<<128, 256, 0, stream>>>(R3, R3a, 64 * 512, 9, 2);
  k_hist<<<(N_EDGES + 255) / 256, 256, 0, stream>>>(edge_index, counts);
  k_scan<<<1, 1024, 0, stream>>>(counts, offsets, cursor);
  k_scatter<<<(N_EDGES + 255) / 256, 256, 0, stream>>>(
      edge_index, edge_attrs, edge_feats, cursor, perm, snd_s, rcv_s, ea_s,
      ef_s);
  k_mlp_mfma<<<N_EDGES / 128, 256, 0, stream>>>(ef_s, rcv_s, R0, R1a, R2a, R3a,
                                                Wd, W, density);
  k_message<<<N_EDGES / 64, 256, 0, stream>>>(snd_s, rcv_s, offsets, ea_s, W, H,
                                              M);
  k_out<<<N_NODES / 8, 256, 0, stream>>>(M, density, Wl0, Wl1, out);
  k_skip_mfma<<<157 + 469, 256, 0, stream>>>(node_feats, node_attrs, Bsw0, Bsw1,
                                             out + (size_t)N_NODES * 512);
}

// Round 7
// 443.034 us; speedup vs baseline: 6.1986x; 1.0287x over previous
//
#include <hip/hip_runtime.h>
#include <hip/hip_bf16.h>
#include <hip/hip_fp16.h>

// Problem constants
#define N_NODES 10000
#define N_EDGES 128000
constexpr int C = 128;
constexpr int A = 10;

constexpr float INV_SQRT_C  = 0.08838834764831845f;   // 1/sqrt(128)
constexpr float INV_SQRT_R  = 0.35355339059327373f;   // 1/sqrt(8)
constexpr float INV_SQRT_64 = 0.125f;                 // 1/sqrt(64)
constexpr float INV_SQRT_CA = 0.027950849718747374f;  // 1/sqrt(1280)
constexpr float INV_SQRT_2C = 0.0625f;                // 1/sqrt(256)
constexpr float INV_SQRT_3  = 0.57735026918962576f;

typedef short short8 __attribute__((ext_vector_type(8)));
typedef _Float16 f16x8 __attribute__((ext_vector_type(8)));
typedef float f32x4 __attribute__((ext_vector_type(4)));

__device__ __forceinline__ float silu_f(float x) { return x / (1.0f + __expf(-x)); }

__device__ __forceinline__ void atomic_add_f32(float* p, float v) {
  __hip_atomic_fetch_add(p, v, __ATOMIC_RELAXED, __HIP_MEMORY_SCOPE_AGENT);
}

__device__ __forceinline__ unsigned short f2bf(float f) {
  unsigned int u = __builtin_bit_cast(unsigned int, f);
  u += 0x7fffu + ((u >> 16) & 1u);  // RNE
  return (unsigned short)(u >> 16);
}

__device__ __forceinline__ unsigned int pk2h(float a, float b) {
  auto h = __builtin_amdgcn_cvt_pkrtz(a, b);  // __fp16 ext_vector(2)
  return __builtin_bit_cast(unsigned int, h);
}

// ---------------------------------------------------------------------------
// K1: H[n, u*4+0] = h0[n,u],  H[n, u*4+1+k] = h1[n,u,k]
// ---------------------------------------------------------------------------
__global__ __launch_bounds__(256) void k_node_up(
    const float* __restrict__ nf, const float* __restrict__ Wu0,
    const float* __restrict__ Wu1, float* __restrict__ H) {
  __shared__ __align__(16) float xs[8][C][4];
  const int t = threadIdx.x;
  const int n0 = blockIdx.x * 8;
  for (int idx = t; idx < 8 * 512; idx += 256) {
    const int nn = idx >> 9, q = idx & 511;
    const float val = nf[(size_t)(n0 + nn) * 512 + q];
    if (q < C) xs[nn][q][0] = val;
    else { const int r = q - C; xs[nn][r / 3][1 + r % 3] = val; }
  }
  __syncthreads();
  const int g = t >> 7, v = t & 127;
  float acc[4][4] = {};
  for (int u = 0; u < C; ++u) {
    const float w0 = Wu0[u * C + v];
    const float w1 = Wu1[u * C + v];
#pragma unroll
    for (int nn = 0; nn < 4; ++nn) {
      const float4 xv = *(const float4*)&xs[g * 4 + nn][u][0];
      acc[nn][0] = fmaf(xv.x, w0, acc[nn][0]);
      acc[nn][1] = fmaf(xv.y, w1, acc[nn][1]);
      acc[nn][2] = fmaf(xv.z, w1, acc[nn][2]);
      acc[nn][3] = fmaf(xv.w, w1, acc[nn][3]);
    }
  }
#pragma unroll
  for (int nn = 0; nn < 4; ++nn) {
    const int n = n0 + g * 4 + nn;
    float4 o;
    o.x = acc[nn][0] * INV_SQRT_C; o.y = acc[nn][1] * INV_SQRT_C;
    o.z = acc[nn][2] * INV_SQRT_C; o.w = acc[nn][3] * INV_SQRT_C;
    *(float4*)&H[(size_t)n * 512 + v * 4] = o;
  }
}

// ---------------------------------------------------------------------------
// k_cvt: pre-convert + B-fragment-swizzle Ws0/Ws1 into bf16 (skip GEMM).
// ---------------------------------------------------------------------------
__global__ __launch_bounds__(256) void k_cvt(
    const float* __restrict__ W0, const float* __restrict__ W1,
    unsigned short* __restrict__ B0, unsigned short* __restrict__ B1) {
  const int idx = blockIdx.x * 256 + threadIdx.x;
  if (idx < 1280 * 128) {
    const int k = idx >> 7, col = idx & 127;
    const int dst = ((k >> 5) * 128 + col) * 32 + (k & 31);
    B0[dst] = f2bf(W0[idx]);
    B1[dst] = f2bf(W1[idx]);
  }
}

// ---------------------------------------------------------------------------
// k_cvt_w: weight (K x N fp32, row-major) -> f16 A-operand swizzle of W^T:
// dst[((n*(K/32) + kt)*32 + kk)] = f16(src[(kt*32+kk)*N + n]).
// ---------------------------------------------------------------------------
__global__ __launch_bounds__(256) void k_cvt_w(
    const float* __restrict__ src, unsigned short* __restrict__ dst,
    int total, int lgN, int KT) {
  const int idx = blockIdx.x * 256 + threadIdx.x;
  if (idx < total) {
    const int k = idx >> lgN;
    const int n = idx & ((1 << lgN) - 1);
    const _Float16 h = (_Float16)src[idx];
    dst[((n * KT + (k >> 5)) << 5) + (k & 31)] =
        __builtin_bit_cast(unsigned short, h);
  }
}

// ---------------------------------------------------------------------------
// K2 (MFMA): sc as two bf16 GEMMs with on-the-fly Z-tile formation.
// ---------------------------------------------------------------------------
__global__ __launch_bounds__(256) void k_skip_mfma(
    const float* __restrict__ nf, const float* __restrict__ attrs,
    const unsigned short* __restrict__ B0, const unsigned short* __restrict__ B1,
    float* __restrict__ out_sc) {
  __shared__ __align__(16) float xs[64][128];      // 32 KB
  __shared__ float at[64][10];                     // 2.5 KB
  __shared__ __align__(16) unsigned short zs[64][40];  // 5 KB

  const int t = threadIdx.x;
  const int wave = t >> 6, lane = t & 63;
  const bool isG0 = blockIdx.x < 157;
  const int r0 = isG0 ? blockIdx.x * 64 : (blockIdx.x - 157) * 64;
  const int rcount = isG0 ? 10000 : 30000;
  const unsigned short* __restrict__ Bsw = isG0 ? B0 : B1;

  for (int idx = t; idx < 64 * 128; idx += 256) {
    const int i = idx >> 7, u = idx & 127;
    const int r = r0 + i;
    float v = 0.f;
    if (r < rcount) {
      if (isG0) v = nf[(size_t)r * 512 + u];
      else {
        const int n = r / 3, kc = r - n * 3;
        v = nf[(size_t)n * 512 + 128 + u * 3 + kc];
      }
    }
    xs[i][u] = v;
  }
  for (int idx = t; idx < 640; idx += 256) {
    const int i = idx / 10, a = idx - (idx / 10) * 10;
    const int r = r0 + i;
    float v = 0.f;
    if (r < rcount) v = attrs[(size_t)(isG0 ? r : r / 3) * 10 + a];
    at[i][a] = v;
  }
  __syncthreads();

  const int m = lane & 15, q = lane >> 4;
  const int colB = wave * 32;

  f32x4 acc[4][2];
#pragma unroll
  for (int rt = 0; rt < 4; ++rt)
#pragma unroll
    for (int ct = 0; ct < 2; ++ct) acc[rt][ct] = (f32x4){0.f, 0.f, 0.f, 0.f};

  for (int kt = 0; kt < 40; ++kt) {
    {
      const int r = t >> 2;
      const int kkb = (t & 3) * 8;
      const int kbase = kt * 32 + kkb;
      unsigned int pk[4];
#pragma unroll
      for (int j = 0; j < 4; ++j) {
        const int k0 = kbase + 2 * j;
        const int u0 = k0 / 10, a0 = k0 - u0 * 10;
        const int k1 = k0 + 1;
        const int u1 = k1 / 10, a1 = k1 - u1 * 10;
        const unsigned short lo = f2bf(xs[r][u0] * at[r][a0]);
        const unsigned short hi = f2bf(xs[r][u1] * at[r][a1]);
        pk[j] = (unsigned int)lo | ((unsigned int)hi << 16);
      }
      *(uint4*)&zs[r][kkb] = make_uint4(pk[0], pk[1], pk[2], pk[3]);
    }
    __syncthreads();

    short8 bfrag[2];
#pragma unroll
    for (int ct = 0; ct < 2; ++ct) {
      const unsigned short* bp =
          &Bsw[(size_t)(kt * 128 + colB + ct * 16 + m) * 32 + q * 8];
      bfrag[ct] = *(const short8*)bp;
    }
#pragma unroll
    for (int rt = 0; rt < 4; ++rt) {
      const short8 afrag = *(const short8*)&zs[rt * 16 + m][q * 8];
#pragma unroll
      for (int ct = 0; ct < 2; ++ct)
        acc[rt][ct] = __builtin_amdgcn_mfma_f32_16x16x32_bf16(
            afrag, bfrag[ct], acc[rt][ct], 0, 0, 0);
    }
    __syncthreads();
  }

#pragma unroll
  for (int rt = 0; rt < 4; ++rt) {
#pragma unroll
    for (int reg = 0; reg < 4; ++reg) {
      const int rloc = rt * 16 + q * 4 + reg;
      const int r = r0 + rloc;
      if (r < rcount) {
#pragma unroll
        for (int ct = 0; ct < 2; ++ct) {
          const int v = colB + ct * 16 + m;
          const float val = acc[rt][ct][reg] * INV_SQRT_CA;
          if (isG0) {
            out_sc[(size_t)r * 512 + v] = val;
          } else {
            const int n = r / 3, kc = r - (r / 3) * 3;
            out_sc[(size_t)n * 512 + 128 + v * 3 + kc] = val;
          }
        }
      }
    }
  }
}

// ---------------------------------------------------------------------------
// Sort-by-receiver: histogram -> scan -> scatter (fills sorted aux arrays)
// ---------------------------------------------------------------------------
__global__ __launch_bounds__(256) void k_hist(const int* __restrict__ eidx,
                                              int* __restrict__ counts) {
  const int e = blockIdx.x * 256 + threadIdx.x;
  if (e < N_EDGES) atomicAdd(&counts[eidx[N_EDGES + e]], 1);
}

__global__ __launch_bounds__(1024) void k_scan(const int* __restrict__ counts,
                                               int* __restrict__ offsets,
                                               int* __restrict__ cursor) {
  __shared__ int part[1024];
  const int t = threadIdx.x;
  int local[10];
  int s = 0;
#pragma unroll
  for (int i = 0; i < 10; ++i) {
    const int idx = t * 10 + i;
    const int c = (idx < N_NODES) ? counts[idx] : 0;
    local[i] = s;
    s += c;
  }
  part[t] = s;
  __syncthreads();
  for (int off = 1; off < 1024; off <<= 1) {
    const int add = (t >= off) ? part[t - off] : 0;
    __syncthreads();
    part[t] += add;
    __syncthreads();
  }
  const int pre = (t > 0) ? part[t - 1] : 0;
#pragma unroll
  for (int i = 0; i < 10; ++i) {
    const int idx = t * 10 + i;
    if (idx < N_NODES) {
      const int o = pre + local[i];
      offsets[idx] = o;
      cursor[idx] = o;
    }
  }
  if (t == 1023) offsets[N_NODES] = part[1023];
}

__global__ __launch_bounds__(256) void k_scatter(
    const int* __restrict__ eidx, const float* __restrict__ ea_g,
    const float* __restrict__ ef_g,
    int* __restrict__ cursor,
    int* __restrict__ snd_s, int* __restrict__ rcv_s,
    float* __restrict__ ea_s, float* __restrict__ ef_s) {
  const int e = blockIdx.x * 256 + threadIdx.x;
  if (e < N_EDGES) {
    const int r = eidx[N_EDGES + e];
    const int pos = atomicAdd(&cursor[r], 1);
    snd_s[pos] = eidx[e];
    rcv_s[pos] = r;
    ((float4*)ea_s)[pos] = ((const float4*)ea_g)[e];
    ((float4*)ef_s)[pos * 2]     = ((const float4*)ef_g)[e * 2];
    ((float4*)ef_s)[pos * 2 + 1] = ((const float4*)ef_g)[e * 2 + 1];
  }
}

// ---------------------------------------------------------------------------
// K3 (fused): edge MLP (MFMA) + message formation + segmented reduction.
// 128 sorted edges/block. L1 VALU -> actA; L2/L3 MFMA; L4 MFMA in 4 chunks of
// 32 edges into LDS wls[32][520] f16 (row skew: 2-way bank alias only), each
// chunk immediately consumed by the segmented message accumulation. W never
// touches HBM. Accumulators (4 f32/thread) persist across chunks; interior
// segments flush with plain float4 stores, boundary segments with atomics.
// ---------------------------------------------------------------------------
__global__ __launch_bounds__(256) void k_mlp_msg(
    const float* __restrict__ ef_s, const float* __restrict__ ea_s,
    const int* __restrict__ snd_s, const int* __restrict__ rcv_s,
    const int* __restrict__ offsets,
    const float* __restrict__ R0, const unsigned short* __restrict__ R1a,
    const unsigned short* __restrict__ R2a, const unsigned short* __restrict__ R3a,
    const float* __restrict__ Wd, const float* __restrict__ H,
    float* __restrict__ M, float* __restrict__ density) {
  __shared__ __align__(16) float efs[128][9];            // 4.5 KB
  __shared__ __align__(16) unsigned short actA[128][72]; // 18 KB
  __shared__ __align__(16) unsigned short actB[128][72]; // 18 KB
  __shared__ __align__(16) __half wls[32][520];          // 33.3 KB
  __shared__ __align__(16) float ys[128][4];             // 2 KB
  __shared__ int sn[128], rc[128];                       // 1 KB
  const int t = threadIdx.x;
  const int wave = t >> 6, lane = t & 63, m = lane & 15, q = lane >> 4;
  const int e0 = blockIdx.x * 128;

  // stage sorted edge feats: 256 threads x float4
  {
    const float4 v = *(const float4*)&ef_s[(size_t)e0 * 8 + t * 4];
    const int e = t >> 1, c0 = (t & 1) * 4;
    efs[e][c0] = v.x; efs[e][c0 + 1] = v.y;
    efs[e][c0 + 2] = v.z; efs[e][c0 + 3] = v.w;
  }
  // stage edge attrs + sender/receiver
  if (t < 128) {
    *(float4*)&ys[t][0] = ((const float4*)ea_s)[e0 + t];
    sn[t] = snd_s[e0 + t];
    rc[t] = rcv_s[e0 + t];
  }
  __syncthreads();

  // density (one thread per edge)
  if (t < 128) {
    float s = 0.f;
#pragma unroll
    for (int i = 0; i < 8; ++i) s = fmaf(efs[t][i], Wd[i], s);
    s *= INV_SQRT_R;
    atomic_add_f32(&density[rc[t]], tanhf(s * s));
  }

  // L1: 8 -> 64 (VALU), silu, f16 into actA. thread: edge t&127, j-half t>>7.
  {
    const int e = t & 127, j0 = (t >> 7) * 32;
    float a[32] = {};
#pragma unroll
    for (int i = 0; i < 8; ++i) {
      const float v = efs[e][i];
#pragma unroll
      for (int jj = 0; jj < 32; ++jj)
        a[jj] = fmaf(v, R0[i * 64 + j0 + jj], a[jj]);
    }
#pragma unroll
    for (int g = 0; g < 8; ++g) {
      uint2 pk;
      pk.x = pk2h(silu_f(a[4 * g] * INV_SQRT_R), silu_f(a[4 * g + 1] * INV_SQRT_R));
      pk.y = pk2h(silu_f(a[4 * g + 2] * INV_SQRT_R), silu_f(a[4 * g + 3] * INV_SQRT_R));
      *(uint2*)&actA[e][j0 + g * 4] = pk;
    }
  }
  __syncthreads();

  // L2: C = R1^T . actA -> silu -> actB.
  {
    const f16x8 af0 = *(const f16x8*)&R1a[(((wave * 16 + m) * 2 + 0) << 5) + q * 8];
    const f16x8 af1 = *(const f16x8*)&R1a[(((wave * 16 + m) * 2 + 1) << 5) + q * 8];
#pragma unroll
    for (int et = 0; et < 8; ++et) {
      const f16x8 bf0 = *(const f16x8*)&actA[et * 16 + m][q * 8];
      const f16x8 bf1 = *(const f16x8*)&actA[et * 16 + m][32 + q * 8];
      f32x4 c = {0.f, 0.f, 0.f, 0.f};
      c = __builtin_amdgcn_mfma_f32_16x16x32_f16(af0, bf0, c, 0, 0, 0);
      c = __builtin_amdgcn_mfma_f32_16x16x32_f16(af1, bf1, c, 0, 0, 0);
      uint2 pk;
      pk.x = pk2h(silu_f(c[0] * INV_SQRT_64), silu_f(c[1] * INV_SQRT_64));
      pk.y = pk2h(silu_f(c[2] * INV_SQRT_64), silu_f(c[3] * INV_SQRT_64));
      *(uint2*)&actB[et * 16 + m][wave * 16 + q * 4] = pk;
    }
  }
  __syncthreads();

  // L3: C = R2^T . actB -> silu -> actA
  {
    const f16x8 af0 = *(const f16x8*)&R2a[(((wave * 16 + m) * 2 + 0) << 5) + q * 8];
    const f16x8 af1 = *(const f16x8*)&R2a[(((wave * 16 + m) * 2 + 1) << 5) + q * 8];
#pragma unroll
    for (int et = 0; et < 8; ++et) {
      const f16x8 bf0 = *(const f16x8*)&actB[et * 16 + m][q * 8];
      const f16x8 bf1 = *(const f16x8*)&actB[et * 16 + m][32 + q * 8];
      f32x4 c = {0.f, 0.f, 0.f, 0.f};
      c = __builtin_amdgcn_mfma_f32_16x16x32_f16(af0, bf0, c, 0, 0, 0);
      c = __builtin_amdgcn_mfma_f32_16x16x32_f16(af1, bf1, c, 0, 0, 0);
      uint2 pk;
      pk.x = pk2h(silu_f(c[0] * INV_SQRT_64), silu_f(c[1] * INV_SQRT_64));
      pk.y = pk2h(silu_f(c[2] * INV_SQRT_64), silu_f(c[3] * INV_SQRT_64));
      *(uint2*)&actA[et * 16 + m][wave * 16 + q * 4] = pk;
    }
  }
  __syncthreads();

  // L4 weights: wave w owns output channels [w*128, (w+1)*128) (j-tiles w*8..)
  f16x8 af[8][2];
#pragma unroll
  for (int jt = 0; jt < 8; ++jt)
#pragma unroll
    for (int kt = 0; kt < 2; ++kt)
      af[jt][kt] = *(const f16x8*)
          &R3a[((((wave * 8 + jt) * 16 + m) * 2 + kt) << 5) + q * 8];

  // message accumulation state
  const int u = t & 127, half = t >> 7;
  float a0 = 0.f, a1 = 0.f, a2 = 0.f, a3 = 0.f;
  int cur = rc[0];

  auto flush = [&](int n) {
    const int s0 = offsets[n], s1 = offsets[n + 1];
    float* Mp = &M[(size_t)n * 1024 + (half << 9) + (u << 2)];
    if (s0 >= e0 && s1 <= e0 + 128) {
      *(float4*)Mp = make_float4(a0, a1, a2, a3);
    } else {
      atomic_add_f32(Mp + 0, a0);
      atomic_add_f32(Mp + 1, a1);
      atomic_add_f32(Mp + 2, a2);
      atomic_add_f32(Mp + 3, a3);
    }
  };

  // 4 chunks of 32 edges: L4 MFMA into LDS, then message accumulation.
#pragma unroll 1
  for (int ch = 0; ch < 4; ++ch) {
    // L4 for edges [ch*32, ch*32+32): et = ch*2, ch*2+1
#pragma unroll
    for (int ei = 0; ei < 2; ++ei) {
      const int et = ch * 2 + ei;
      const f16x8 bf0 = *(const f16x8*)&actA[et * 16 + m][q * 8];
      const f16x8 bf1 = *(const f16x8*)&actA[et * 16 + m][32 + q * 8];
#pragma unroll
      for (int jt = 0; jt < 8; ++jt) {
        f32x4 c = {0.f, 0.f, 0.f, 0.f};
        c = __builtin_amdgcn_mfma_f32_16x16x32_f16(af[jt][0], bf0, c, 0, 0, 0);
        c = __builtin_amdgcn_mfma_f32_16x16x32_f16(af[jt][1], bf1, c, 0, 0, 0);
        uint2 pk;
        pk.x = pk2h(c[0] * INV_SQRT_64, c[1] * INV_SQRT_64);
        pk.y = pk2h(c[2] * INV_SQRT_64, c[3] * INV_SQRT_64);
        *(uint2*)&wls[ei * 16 + m][(wave * 8 + jt) * 16 + q * 4] = pk;
      }
    }
    __syncthreads();

    // message accumulation for this chunk's 32 edges
#pragma unroll 1
    for (int le = 0; le < 32; ++le) {
      const int eb = ch * 32 + le;
      const int n = rc[eb];
      if (n != cur) {  // wave-uniform
        flush(cur);
        a0 = a1 = a2 = a3 = 0.f;
        cur = n;
      }
      const int s = sn[eb];
      const float4 h4 = *(const float4*)&H[(size_t)s * 512 + (u << 2)];
      const float y0 = ys[eb][0];
      const float y1x = ys[eb][1], y1y = ys[eb][2], y1z = ys[eb][3];
      if (half == 0) {
        const float w1v = __half2float(wls[le][u]);
        const float w2v = __half2float(wls[le][128 + u]);
        a0 = fmaf(w1v * h4.x, y0, a0);
        const float c1 = w2v * h4.x;
        a1 = fmaf(c1, y1x, a1);
        a2 = fmaf(c1, y1y, a2);
        a3 = fmaf(c1, y1z, a3);
      } else {
        const float w3v = __half2float(wls[le][256 + u]);
        const float w4v = __half2float(wls[le][384 + u]);
        const float dt = h4.y * y1x + h4.z * y1y + h4.w * y1z;
        a0 = fmaf(w4v * dt, INV_SQRT_3, a0);
        const float c3 = w3v * y0;
        a1 = fmaf(c3, h4.y, a1);
        a2 = fmaf(c3, h4.z, a2);
        a3 = fmaf(c3, h4.w, a3);
      }
    }
    __syncthreads();  // before next chunk overwrites wls
  }
  flush(cur);
}

// ---------------------------------------------------------------------------
// K5: out0 = M0 @ Wl0 /16/denom; out1[.,.,k] = M1[...,k] @ Wl1 /16/denom
// ---------------------------------------------------------------------------
__global__ __launch_bounds__(256) void k_out(
    const float* __restrict__ M, const float* __restrict__ density,
    const float* __restrict__ Wl0, const float* __restrict__ Wl1,
    float* __restrict__ out) {
  __shared__ __align__(16) float Ms[8][256][4];  // 32 KB
  __shared__ float dens[8];
  const int t = threadIdx.x;
  const int n0 = blockIdx.x * 8;
  const float4* Msrc = (const float4*)&M[(size_t)n0 * 1024];
  float4* Mdst = (float4*)&Ms[0][0][0];
  for (int idx = t; idx < 8 * 256; idx += 256) Mdst[idx] = Msrc[idx];
  if (t < 8) dens[t] = density[n0 + t] + 1.0f;
  __syncthreads();
  const int g = t >> 7, v = t & 127;
  float acc[4][4] = {};
  for (int p0 = 0; p0 < 256; p0 += 4) {
    float4 mv[4][4];
#pragma unroll
    for (int nn = 0; nn < 4; ++nn)
#pragma unroll
      for (int j = 0; j < 4; ++j)
        mv[nn][j] = *(const float4*)&Ms[g * 4 + nn][p0 + j][0];
#pragma unroll
    for (int j = 0; j < 4; ++j) {
      const float w0 = Wl0[(p0 + j) * C + v];
      const float w1 = Wl1[(p0 + j) * C + v];
#pragma unroll
      for (int nn = 0; nn < 4; ++nn) {
        acc[nn][0] = fmaf(mv[nn][j].x, w0, acc[nn][0]);
        acc[nn][1] = fmaf(mv[nn][j].y, w1, acc[nn][1]);
        acc[nn][2] = fmaf(mv[nn][j].z, w1, acc[nn][2]);
        acc[nn][3] = fmaf(mv[nn][j].w, w1, acc[nn][3]);
      }
    }
  }
#pragma unroll
  for (int nn = 0; nn < 4; ++nn) {
    const int n = n0 + g * 4 + nn;
    const float sc = INV_SQRT_2C / dens[g * 4 + nn];
    float4 o;
    o.x = acc[nn][0] * sc; o.y = acc[nn][1] * sc;
    o.z = acc[nn][2] * sc; o.w = acc[nn][3] * sc;
    *(float4*)&out[(size_t)n * 512 + v * 4] = o;
  }
}

// ---------------------------------------------------------------------------
extern "C" void kernel_launch(void* const* d_in, const int* in_sizes, int n_in,
                              void* d_out, int out_size, void* d_ws, size_t ws_size,
                              hipStream_t stream) {
  const float* node_attrs = (const float*)d_in[0];
  const float* node_feats = (const float*)d_in[1];
  const float* edge_attrs = (const float*)d_in[2];
  const float* edge_feats = (const float*)d_in[3];
  const int*   edge_index = (const int*)d_in[4];
  const float* W_up0 = (const float*)d_in[5];
  const float* W_up1 = (const float*)d_in[6];
  const float* R0 = (const float*)d_in[7];
  const float* R1 = (const float*)d_in[8];
  const float* R2 = (const float*)d_in[9];
  const float* R3 = (const float*)d_in[10];
  const float* Wd  = (const float*)d_in[11];
  const float* Wl0 = (const float*)d_in[12];
  const float* Wl1 = (const float*)d_in[13];
  const float* Ws0 = (const float*)d_in[14];
  const float* Ws1 = (const float*)d_in[15];
  float* out = (float*)d_out;

  // Workspace layout:
  // H | M | density | counts | offsets | cursor | snd_s | rcv_s |
  // ea_s | Bsw0 | Bsw1 | R1a | R2a | R3a (ushort) | ef_s
  float* H = (float*)d_ws;
  float* M = H + (size_t)N_NODES * 512;
  float* density = M + (size_t)N_NODES * 1024;
  int* counts  = (int*)(density + 10000);
  int* offsets = counts + 10016;
  int* cursor  = offsets + 10016;
  int* snd_s   = cursor + 10016;
  int* rcv_s   = snd_s + N_EDGES;
  float* ea_s  = (float*)(rcv_s + N_EDGES);
  unsigned short* Bsw0 = (unsigned short*)(ea_s + (size_t)N_EDGES * 4);
  unsigned short* Bsw1 = Bsw0 + 1280 * 128;
  unsigned short* R1a  = Bsw1 + 1280 * 128;
  unsigned short* R2a  = R1a + 64 * 64;
  unsigned short* R3a  = R2a + 64 * 64;
  float* ef_s  = (float*)(R3a + 64 * 512);

  // zero M + density + counts (contiguous)
  hipMemsetAsync(M, 0, ((size_t)N_NODES * 1024 + 10000 + 10016) * sizeof(float),
                 stream);

  k_node_up<<<N_NODES / 8, 256, 0, stream>>>(node_feats, W_up0, W_up1, H);
  k_cvt<<<640, 256, 0, stream>>>(Ws0, Ws1, Bsw0, Bsw1);
  k_cvt_w<<<16, 256, 0, stream>>>(R1, R1a, 64 * 64, 6, 2);
  k_cvt_w<<<16, 256, 0, stream>>>(R2, R2a, 64 * 64, 6, 2);
  k_cvt_w<<<128, 256, 0, stream>>>(R3, R3a, 64 * 512, 9, 2);
  k_hist<<<(N_EDGES + 255) / 256, 256, 0, stream>>>(edge_index, counts);
  k_scan<<<1, 1024, 0, stream>>>(counts, offsets, cursor);
  k_scatter<<<(N_EDGES + 255) / 256, 256, 0, stream>>>(
      edge_index, edge_attrs, edge_feats, cursor, snd_s, rcv_s, ea_s, ef_s);
  k_mlp_msg<<<N_EDGES / 128, 256, 0, stream>>>(ef_s, ea_s, snd_s, rcv_s,
                                               offsets, R0, R1a, R2a, R3a, Wd,
                                               H, M, density);
  k_out<<<N_NODES / 8, 256, 0, stream>>>(M, density, Wl0, Wl1, out);
  k_skip_mfma<<<157 + 469, 256, 0, stream>>>(node_feats, node_attrs, Bsw0, Bsw1,
                                             out + (size_t)N_NODES * 512);
}

// Round 8
// 420.943 us; speedup vs baseline: 6.5239x; 1.0525x over previous
//
#include <hip/hip_runtime.h>
#include <hip/hip_bf16.h>
#include <hip/hip_fp16.h>

// Problem constants
#define N_NODES 10000
#define N_EDGES 128000
constexpr int C = 128;
constexpr int A = 10;

constexpr float INV_SQRT_C  = 0.08838834764831845f;   // 1/sqrt(128)
constexpr float INV_SQRT_R  = 0.35355339059327373f;   // 1/sqrt(8)
constexpr float INV_SQRT_64 = 0.125f;                 // 1/sqrt(64)
constexpr float INV_SQRT_CA = 0.027950849718747374f;  // 1/sqrt(1280)
constexpr float INV_SQRT_2C = 0.0625f;                // 1/sqrt(256)
constexpr float INV_SQRT_3  = 0.57735026918962576f;

typedef short short8 __attribute__((ext_vector_type(8)));
typedef _Float16 f16x8 __attribute__((ext_vector_type(8)));
typedef float f32x4 __attribute__((ext_vector_type(4)));

__device__ __forceinline__ float silu_f(float x) { return x / (1.0f + __expf(-x)); }

__device__ __forceinline__ void atomic_add_f32(float* p, float v) {
  __hip_atomic_fetch_add(p, v, __ATOMIC_RELAXED, __HIP_MEMORY_SCOPE_AGENT);
}

__device__ __forceinline__ unsigned short f2bf(float f) {
  unsigned int u = __builtin_bit_cast(unsigned int, f);
  u += 0x7fffu + ((u >> 16) & 1u);  // RNE
  return (unsigned short)(u >> 16);
}

__device__ __forceinline__ float bf2f(unsigned short us) {
  return __builtin_bit_cast(float, (unsigned int)us << 16);
}

__device__ __forceinline__ unsigned int pk2h(float a, float b) {
  auto h = __builtin_amdgcn_cvt_pkrtz(a, b);  // __fp16 ext_vector(2)
  return __builtin_bit_cast(unsigned int, h);
}

__device__ __forceinline__ float4 h4tof4(uint2 v) {
  const __half2 lo = __builtin_bit_cast(__half2, v.x);
  const __half2 hi = __builtin_bit_cast(__half2, v.y);
  const float2 flo = __half22float2(lo), fhi = __half22float2(hi);
  return make_float4(flo.x, flo.y, fhi.x, fhi.y);
}

// ---------------------------------------------------------------------------
// K1: Hh[n, u*4+0] = h0[n,u],  Hh[n, u*4+1+k] = h1[n,u,k]  (fp16 output)
// ---------------------------------------------------------------------------
__global__ __launch_bounds__(256) void k_node_up(
    const float* __restrict__ nf, const float* __restrict__ Wu0,
    const float* __restrict__ Wu1, __half* __restrict__ Hh) {
  __shared__ __align__(16) float xs[8][C][4];
  const int t = threadIdx.x;
  const int n0 = blockIdx.x * 8;
  for (int idx = t; idx < 8 * 512; idx += 256) {
    const int nn = idx >> 9, q = idx & 511;
    const float val = nf[(size_t)(n0 + nn) * 512 + q];
    if (q < C) xs[nn][q][0] = val;
    else { const int r = q - C; xs[nn][r / 3][1 + r % 3] = val; }
  }
  __syncthreads();
  const int g = t >> 7, v = t & 127;
  float acc[4][4] = {};
  for (int u = 0; u < C; ++u) {
    const float w0 = Wu0[u * C + v];
    const float w1 = Wu1[u * C + v];
#pragma unroll
    for (int nn = 0; nn < 4; ++nn) {
      const float4 xv = *(const float4*)&xs[g * 4 + nn][u][0];
      acc[nn][0] = fmaf(xv.x, w0, acc[nn][0]);
      acc[nn][1] = fmaf(xv.y, w1, acc[nn][1]);
      acc[nn][2] = fmaf(xv.z, w1, acc[nn][2]);
      acc[nn][3] = fmaf(xv.w, w1, acc[nn][3]);
    }
  }
#pragma unroll
  for (int nn = 0; nn < 4; ++nn) {
    const int n = n0 + g * 4 + nn;
    uint2 o;
    o.x = pk2h(acc[nn][0] * INV_SQRT_C, acc[nn][1] * INV_SQRT_C);
    o.y = pk2h(acc[nn][2] * INV_SQRT_C, acc[nn][3] * INV_SQRT_C);
    *(uint2*)&Hh[(size_t)n * 512 + v * 4] = o;
  }
}

// ---------------------------------------------------------------------------
// k_cvt: pre-convert + B-fragment-swizzle Ws0/Ws1 into bf16 (skip GEMM).
// ---------------------------------------------------------------------------
__global__ __launch_bounds__(256) void k_cvt(
    const float* __restrict__ W0, const float* __restrict__ W1,
    unsigned short* __restrict__ B0, unsigned short* __restrict__ B1) {
  const int idx = blockIdx.x * 256 + threadIdx.x;
  if (idx < 1280 * 128) {
    const int k = idx >> 7, col = idx & 127;
    const int dst = ((k >> 5) * 128 + col) * 32 + (k & 31);
    B0[dst] = f2bf(W0[idx]);
    B1[dst] = f2bf(W1[idx]);
  }
}

// ---------------------------------------------------------------------------
// k_cvt_w: weight (K x N fp32, row-major) -> f16 A-operand swizzle of W^T.
// ---------------------------------------------------------------------------
__global__ __launch_bounds__(256) void k_cvt_w(
    const float* __restrict__ src, unsigned short* __restrict__ dst,
    int total, int lgN, int KT) {
  const int idx = blockIdx.x * 256 + threadIdx.x;
  if (idx < total) {
    const int k = idx >> lgN;
    const int n = idx & ((1 << lgN) - 1);
    const _Float16 h = (_Float16)src[idx];
    dst[((n * KT + (k >> 5)) << 5) + (k & 31)] =
        __builtin_bit_cast(unsigned short, h);
  }
}

// ---------------------------------------------------------------------------
// K2 (MFMA): sc as two bf16 GEMMs; bf16 x-stage (16 KB) + double-buffered zs
// -> one barrier per K-step, 5 blocks/CU.
// ---------------------------------------------------------------------------
__global__ __launch_bounds__(256) void k_skip_mfma(
    const float* __restrict__ nf, const float* __restrict__ attrs,
    const unsigned short* __restrict__ B0, const unsigned short* __restrict__ B1,
    float* __restrict__ out_sc) {
  __shared__ __align__(16) unsigned short xs[64][128];     // 16 KB bf16
  __shared__ float at[64][10];                             // 2.5 KB
  __shared__ __align__(16) unsigned short zs[2][64][40];   // 10.25 KB

  const int t = threadIdx.x;
  const int wave = t >> 6, lane = t & 63;
  const bool isG0 = blockIdx.x < 157;
  const int r0 = isG0 ? blockIdx.x * 64 : (blockIdx.x - 157) * 64;
  const int rcount = isG0 ? 10000 : 30000;
  const unsigned short* __restrict__ Bsw = isG0 ? B0 : B1;

  for (int idx = t; idx < 64 * 128; idx += 256) {
    const int i = idx >> 7, u = idx & 127;
    const int r = r0 + i;
    float v = 0.f;
    if (r < rcount) {
      if (isG0) v = nf[(size_t)r * 512 + u];
      else {
        const int n = r / 3, kc = r - n * 3;
        v = nf[(size_t)n * 512 + 128 + u * 3 + kc];
      }
    }
    xs[i][u] = f2bf(v);
  }
  for (int idx = t; idx < 640; idx += 256) {
    const int i = idx / 10, a = idx - (idx / 10) * 10;
    const int r = r0 + i;
    float v = 0.f;
    if (r < rcount) v = attrs[(size_t)(isG0 ? r : r / 3) * 10 + a];
    at[i][a] = v;
  }
  __syncthreads();

  const int m = lane & 15, q = lane >> 4;
  const int colB = wave * 32;

  f32x4 acc[4][2];
#pragma unroll
  for (int rt = 0; rt < 4; ++rt)
#pragma unroll
    for (int ct = 0; ct < 2; ++ct) acc[rt][ct] = (f32x4){0.f, 0.f, 0.f, 0.f};

  for (int kt = 0; kt < 40; ++kt) {
    const int buf = kt & 1;
    {
      const int r = t >> 2;
      const int kkb = (t & 3) * 8;
      const int kbase = kt * 32 + kkb;
      unsigned int pk[4];
#pragma unroll
      for (int j = 0; j < 4; ++j) {
        const int k0 = kbase + 2 * j;
        const int u0 = k0 / 10, a0 = k0 - u0 * 10;
        const int k1 = k0 + 1;
        const int u1 = k1 / 10, a1 = k1 - u1 * 10;
        const unsigned short lo = f2bf(bf2f(xs[r][u0]) * at[r][a0]);
        const unsigned short hi = f2bf(bf2f(xs[r][u1]) * at[r][a1]);
        pk[j] = (unsigned int)lo | ((unsigned int)hi << 16);
      }
      *(uint4*)&zs[buf][r][kkb] = make_uint4(pk[0], pk[1], pk[2], pk[3]);
    }
    __syncthreads();

    short8 bfrag[2];
#pragma unroll
    for (int ct = 0; ct < 2; ++ct) {
      const unsigned short* bp =
          &Bsw[(size_t)(kt * 128 + colB + ct * 16 + m) * 32 + q * 8];
      bfrag[ct] = *(const short8*)bp;
    }
#pragma unroll
    for (int rt = 0; rt < 4; ++rt) {
      const short8 afrag = *(const short8*)&zs[buf][rt * 16 + m][q * 8];
#pragma unroll
      for (int ct = 0; ct < 2; ++ct)
        acc[rt][ct] = __builtin_amdgcn_mfma_f32_16x16x32_bf16(
            afrag, bfrag[ct], acc[rt][ct], 0, 0, 0);
    }
    // no trailing barrier: next iteration writes the other zs buffer
  }

#pragma unroll
  for (int rt = 0; rt < 4; ++rt) {
#pragma unroll
    for (int reg = 0; reg < 4; ++reg) {
      const int rloc = rt * 16 + q * 4 + reg;
      const int r = r0 + rloc;
      if (r < rcount) {
#pragma unroll
        for (int ct = 0; ct < 2; ++ct) {
          const int v = colB + ct * 16 + m;
          const float val = acc[rt][ct][reg] * INV_SQRT_CA;
          if (isG0) {
            out_sc[(size_t)r * 512 + v] = val;
          } else {
            const int n = r / 3, kc = r - (r / 3) * 3;
            out_sc[(size_t)n * 512 + 128 + v * 3 + kc] = val;
          }
        }
      }
    }
  }
}

// ---------------------------------------------------------------------------
// Sort-by-receiver: histogram -> scan -> scatter (fills sorted aux arrays)
// ---------------------------------------------------------------------------
__global__ __launch_bounds__(256) void k_hist(const int* __restrict__ eidx,
                                              int* __restrict__ counts) {
  const int e = blockIdx.x * 256 + threadIdx.x;
  if (e < N_EDGES) atomicAdd(&counts[eidx[N_EDGES + e]], 1);
}

__global__ __launch_bounds__(1024) void k_scan(const int* __restrict__ counts,
                                               int* __restrict__ offsets,
                                               int* __restrict__ cursor) {
  __shared__ int part[1024];
  const int t = threadIdx.x;
  int local[10];
  int s = 0;
#pragma unroll
  for (int i = 0; i < 10; ++i) {
    const int idx = t * 10 + i;
    const int c = (idx < N_NODES) ? counts[idx] : 0;
    local[i] = s;
    s += c;
  }
  part[t] = s;
  __syncthreads();
  for (int off = 1; off < 1024; off <<= 1) {
    const int add = (t >= off) ? part[t - off] : 0;
    __syncthreads();
    part[t] += add;
    __syncthreads();
  }
  const int pre = (t > 0) ? part[t - 1] : 0;
#pragma unroll
  for (int i = 0; i < 10; ++i) {
    const int idx = t * 10 + i;
    if (idx < N_NODES) {
      const int o = pre + local[i];
      offsets[idx] = o;
      cursor[idx] = o;
    }
  }
  if (t == 1023) offsets[N_NODES] = part[1023];
}

__global__ __launch_bounds__(256) void k_scatter(
    const int* __restrict__ eidx, const float* __restrict__ ea_g,
    const float* __restrict__ ef_g,
    int* __restrict__ cursor,
    int* __restrict__ snd_s, int* __restrict__ rcv_s,
    float* __restrict__ ea_s, float* __restrict__ ef_s) {
  const int e = blockIdx.x * 256 + threadIdx.x;
  if (e < N_EDGES) {
    const int r = eidx[N_EDGES + e];
    const int pos = atomicAdd(&cursor[r], 1);
    snd_s[pos] = eidx[e];
    rcv_s[pos] = r;
    ((float4*)ea_s)[pos] = ((const float4*)ea_g)[e];
    ((float4*)ef_s)[pos * 2]     = ((const float4*)ef_g)[e * 2];
    ((float4*)ef_s)[pos * 2 + 1] = ((const float4*)ef_g)[e * 2 + 1];
  }
}

// ---------------------------------------------------------------------------
// K3 (fused): edge MLP (MFMA) + message formation + segmented reduction.
// Pair-tile L4: wave w computes channel tiles {base..base+3} U {base+8..+11}
// (base = (w&1)*4 + (w>>1)*16), so each lane holds channel pairs (c, c+128)
// (or (256+c, 384+c)) and writes them interleaved -> message loop reads ONE
// ds_read_b32 per edge. H gathered as fp16 with depth-2 software prefetch.
// ---------------------------------------------------------------------------
__global__ __launch_bounds__(256) void k_mlp_msg(
    const float* __restrict__ ef_s, const float* __restrict__ ea_s,
    const int* __restrict__ snd_s, const int* __restrict__ rcv_s,
    const int* __restrict__ offsets,
    const float* __restrict__ R0, const unsigned short* __restrict__ R1a,
    const unsigned short* __restrict__ R2a, const unsigned short* __restrict__ R3a,
    const float* __restrict__ Wd, const __half* __restrict__ Hh,
    float* __restrict__ M, float* __restrict__ density) {
  __shared__ __align__(16) float efs[128][9];            // 4.5 KB
  __shared__ __align__(16) unsigned short actA[128][72]; // 18 KB
  __shared__ __align__(16) unsigned short actB[128][72]; // 18 KB
  __shared__ __align__(16) __half wls2[32][536];         // 33.5 KB (row=1072B)
  __shared__ __align__(16) float ys[128][4];             // 2 KB
  __shared__ int sn[128], rc[128];                       // 1 KB
  const int t = threadIdx.x;
  const int wave = t >> 6, lane = t & 63, m = lane & 15, q = lane >> 4;
  const int e0 = blockIdx.x * 128;

  // stage sorted edge feats: 256 threads x float4
  {
    const float4 v = *(const float4*)&ef_s[(size_t)e0 * 8 + t * 4];
    const int e = t >> 1, c0 = (t & 1) * 4;
    efs[e][c0] = v.x; efs[e][c0 + 1] = v.y;
    efs[e][c0 + 2] = v.z; efs[e][c0 + 3] = v.w;
  }
  if (t < 128) {
    *(float4*)&ys[t][0] = ((const float4*)ea_s)[e0 + t];
    sn[t] = snd_s[e0 + t];
    rc[t] = rcv_s[e0 + t];
  }
  __syncthreads();

  const int u = t & 127, half = t >> 7;
  // depth-2 H prefetch (issued early; consumed in the message loop)
  uint2 hp0 = *(const uint2*)&Hh[(size_t)sn[0] * 512 + (u << 2)];
  uint2 hp1 = *(const uint2*)&Hh[(size_t)sn[1] * 512 + (u << 2)];

  // density (one thread per edge)
  if (t < 128) {
    float s = 0.f;
#pragma unroll
    for (int i = 0; i < 8; ++i) s = fmaf(efs[t][i], Wd[i], s);
    s *= INV_SQRT_R;
    atomic_add_f32(&density[rc[t]], tanhf(s * s));
  }

  // L1: 8 -> 64 (VALU), silu, f16 into actA.
  {
    const int e = t & 127, j0 = (t >> 7) * 32;
    float a[32] = {};
#pragma unroll
    for (int i = 0; i < 8; ++i) {
      const float v = efs[e][i];
#pragma unroll
      for (int jj = 0; jj < 32; ++jj)
        a[jj] = fmaf(v, R0[i * 64 + j0 + jj], a[jj]);
    }
#pragma unroll
    for (int g = 0; g < 8; ++g) {
      uint2 pk;
      pk.x = pk2h(silu_f(a[4 * g] * INV_SQRT_R), silu_f(a[4 * g + 1] * INV_SQRT_R));
      pk.y = pk2h(silu_f(a[4 * g + 2] * INV_SQRT_R), silu_f(a[4 * g + 3] * INV_SQRT_R));
      *(uint2*)&actA[e][j0 + g * 4] = pk;
    }
  }
  __syncthreads();

  // L2: C = R1^T . actA -> silu -> actB.
  {
    const f16x8 af0 = *(const f16x8*)&R1a[(((wave * 16 + m) * 2 + 0) << 5) + q * 8];
    const f16x8 af1 = *(const f16x8*)&R1a[(((wave * 16 + m) * 2 + 1) << 5) + q * 8];
#pragma unroll
    for (int et = 0; et < 8; ++et) {
      const f16x8 bf0 = *(const f16x8*)&actA[et * 16 + m][q * 8];
      const f16x8 bf1 = *(const f16x8*)&actA[et * 16 + m][32 + q * 8];
      f32x4 c = {0.f, 0.f, 0.f, 0.f};
      c = __builtin_amdgcn_mfma_f32_16x16x32_f16(af0, bf0, c, 0, 0, 0);
      c = __builtin_amdgcn_mfma_f32_16x16x32_f16(af1, bf1, c, 0, 0, 0);
      uint2 pk;
      pk.x = pk2h(silu_f(c[0] * INV_SQRT_64), silu_f(c[1] * INV_SQRT_64));
      pk.y = pk2h(silu_f(c[2] * INV_SQRT_64), silu_f(c[3] * INV_SQRT_64));
      *(uint2*)&actB[et * 16 + m][wave * 16 + q * 4] = pk;
    }
  }
  __syncthreads();

  // L3: C = R2^T . actB -> silu -> actA
  {
    const f16x8 af0 = *(const f16x8*)&R2a[(((wave * 16 + m) * 2 + 0) << 5) + q * 8];
    const f16x8 af1 = *(const f16x8*)&R2a[(((wave * 16 + m) * 2 + 1) << 5) + q * 8];
#pragma unroll
    for (int et = 0; et < 8; ++et) {
      const f16x8 bf0 = *(const f16x8*)&actB[et * 16 + m][q * 8];
      const f16x8 bf1 = *(const f16x8*)&actB[et * 16 + m][32 + q * 8];
      f32x4 c = {0.f, 0.f, 0.f, 0.f};
      c = __builtin_amdgcn_mfma_f32_16x16x32_f16(af0, bf0, c, 0, 0, 0);
      c = __builtin_amdgcn_mfma_f32_16x16x32_f16(af1, bf1, c, 0, 0, 0);
      uint2 pk;
      pk.x = pk2h(silu_f(c[0] * INV_SQRT_64), silu_f(c[1] * INV_SQRT_64));
      pk.y = pk2h(silu_f(c[2] * INV_SQRT_64), silu_f(c[3] * INV_SQRT_64));
      *(uint2*)&actA[et * 16 + m][wave * 16 + q * 4] = pk;
    }
  }
  __syncthreads();

  // L4 weights, pair-tile assignment: lower tile JL, partner JH = JL + 8.
  const int baseJ = (wave & 1) * 4 + (wave >> 1) * 16;
  f16x8 afL[4][2], afH[4][2];
#pragma unroll
  for (int i = 0; i < 4; ++i) {
#pragma unroll
    for (int kt = 0; kt < 2; ++kt) {
      const int JL = baseJ + i, JH = JL + 8;
      afL[i][kt] = *(const f16x8*)&R3a[(((JL * 16 + m) * 2 + kt) << 5) + q * 8];
      afH[i][kt] = *(const f16x8*)&R3a[(((JH * 16 + m) * 2 + kt) << 5) + q * 8];
    }
  }

  // message accumulation state
  float a0 = 0.f, a1 = 0.f, a2 = 0.f, a3 = 0.f;
  int cur = rc[0];

  auto flush = [&](int n) {
    const int s0 = offsets[n], s1 = offsets[n + 1];
    float* Mp = &M[(size_t)n * 1024 + (half << 9) + (u << 2)];
    if (s0 >= e0 && s1 <= e0 + 128) {
      *(float4*)Mp = make_float4(a0, a1, a2, a3);
    } else {
      atomic_add_f32(Mp + 0, a0);
      atomic_add_f32(Mp + 1, a1);
      atomic_add_f32(Mp + 2, a2);
      atomic_add_f32(Mp + 3, a3);
    }
  };

  // 4 chunks of 32 edges: L4 MFMA into LDS (interleaved pairs), then messages.
#pragma unroll 1
  for (int ch = 0; ch < 4; ++ch) {
#pragma unroll
    for (int ei = 0; ei < 2; ++ei) {
      const int et = ch * 2 + ei;
      const f16x8 bf0 = *(const f16x8*)&actA[et * 16 + m][q * 8];
      const f16x8 bf1 = *(const f16x8*)&actA[et * 16 + m][32 + q * 8];
#pragma unroll
      for (int i = 0; i < 4; ++i) {
        f32x4 cL = {0.f, 0.f, 0.f, 0.f}, cH = {0.f, 0.f, 0.f, 0.f};
        cL = __builtin_amdgcn_mfma_f32_16x16x32_f16(afL[i][0], bf0, cL, 0, 0, 0);
        cL = __builtin_amdgcn_mfma_f32_16x16x32_f16(afL[i][1], bf1, cL, 0, 0, 0);
        cH = __builtin_amdgcn_mfma_f32_16x16x32_f16(afH[i][0], bf0, cH, 0, 0, 0);
        cH = __builtin_amdgcn_mfma_f32_16x16x32_f16(afH[i][1], bf1, cH, 0, 0, 0);
        uint4 pk;
        pk.x = pk2h(cL[0] * INV_SQRT_64, cH[0] * INV_SQRT_64);
        pk.y = pk2h(cL[1] * INV_SQRT_64, cH[1] * INV_SQRT_64);
        pk.z = pk2h(cL[2] * INV_SQRT_64, cH[2] * INV_SQRT_64);
        pk.w = pk2h(cL[3] * INV_SQRT_64, cH[3] * INV_SQRT_64);
        const int JL = baseJ + i;
        const int pidx0 = ((JL < 8) ? JL * 16 : (JL - 16) * 16 + 128) + q * 4;
        *(uint4*)&wls2[ei * 16 + m][pidx0 * 2] = pk;
      }
    }
    __syncthreads();

    // message accumulation for this chunk's 32 edges (depth-2 H prefetch)
#pragma unroll 1
    for (int le = 0; le < 32; ++le) {
      const int eb = ch * 32 + le;
      const int n = rc[eb];
      if (n != cur) {  // wave-uniform
        flush(cur);
        a0 = a1 = a2 = a3 = 0.f;
        cur = n;
      }
      const int nb = (eb + 2 < 128) ? eb + 2 : 127;
      const uint2 hnx = *(const uint2*)&Hh[(size_t)sn[nb] * 512 + (u << 2)];
      const float4 h4 = h4tof4(hp0);
      const unsigned int pr =
          *(const unsigned int*)&wls2[le][(half ? 128 + u : u) * 2];
      const __half2 ph = __builtin_bit_cast(__half2, pr);
      const float2 pw = __half22float2(ph);
      const float y0 = ys[eb][0];
      const float y1x = ys[eb][1], y1y = ys[eb][2], y1z = ys[eb][3];
      if (half == 0) {
        a0 = fmaf(pw.x * h4.x, y0, a0);
        const float c1 = pw.y * h4.x;
        a1 = fmaf(c1, y1x, a1);
        a2 = fmaf(c1, y1y, a2);
        a3 = fmaf(c1, y1z, a3);
      } else {
        const float dt = h4.y * y1x + h4.z * y1y + h4.w * y1z;
        a0 = fmaf(pw.y * dt, INV_SQRT_3, a0);
        const float c3 = pw.x * y0;
        a1 = fmaf(c3, h4.y, a1);
        a2 = fmaf(c3, h4.z, a2);
        a3 = fmaf(c3, h4.w, a3);
      }
      hp0 = hp1;
      hp1 = hnx;
    }
    __syncthreads();  // before next chunk overwrites wls2
  }
  flush(cur);
}

// ---------------------------------------------------------------------------
// K5: out0 = M0 @ Wl0 /16/denom; out1[.,.,k] = M1[...,k] @ Wl1 /16/denom
// ---------------------------------------------------------------------------
__global__ __launch_bounds__(256) void k_out(
    const float* __restrict__ M, const float* __restrict__ density,
    const float* __restrict__ Wl0, const float* __restrict__ Wl1,
    float* __restrict__ out) {
  __shared__ __align__(16) float Ms[8][256][4];  // 32 KB
  __shared__ float dens[8];
  const int t = threadIdx.x;
  const int n0 = blockIdx.x * 8;
  const float4* Msrc = (const float4*)&M[(size_t)n0 * 1024];
  float4* Mdst = (float4*)&Ms[0][0][0];
  for (int idx = t; idx < 8 * 256; idx += 256) Mdst[idx] = Msrc[idx];
  if (t < 8) dens[t] = density[n0 + t] + 1.0f;
  __syncthreads();
  const int g = t >> 7, v = t & 127;
  float acc[4][4] = {};
  for (int p0 = 0; p0 < 256; p0 += 4) {
    float4 mv[4][4];
#pragma unroll
    for (int nn = 0; nn < 4; ++nn)
#pragma unroll
      for (int j = 0; j < 4; ++j)
        mv[nn][j] = *(const float4*)&Ms[g * 4 + nn][p0 + j][0];
#pragma unroll
    for (int j = 0; j < 4; ++j) {
      const float w0 = Wl0[(p0 + j) * C + v];
      const float w1 = Wl1[(p0 + j) * C + v];
#pragma unroll
      for (int nn = 0; nn < 4; ++nn) {
        acc[nn][0] = fmaf(mv[nn][j].x, w0, acc[nn][0]);
        acc[nn][1] = fmaf(mv[nn][j].y, w1, acc[nn][1]);
        acc[nn][2] = fmaf(mv[nn][j].z, w1, acc[nn][2]);
        acc[nn][3] = fmaf(mv[nn][j].w, w1, acc[nn][3]);
      }
    }
  }
#pragma unroll
  for (int nn = 0; nn < 4; ++nn) {
    const int n = n0 + g * 4 + nn;
    const float sc = INV_SQRT_2C / dens[g * 4 + nn];
    float4 o;
    o.x = acc[nn][0] * sc; o.y = acc[nn][1] * sc;
    o.z = acc[nn][2] * sc; o.w = acc[nn][3] * sc;
    *(float4*)&out[(size_t)n * 512 + v * 4] = o;
  }
}

// ---------------------------------------------------------------------------
extern "C" void kernel_launch(void* const* d_in, const int* in_sizes, int n_in,
                              void* d_out, int out_size, void* d_ws, size_t ws_size,
                              hipStream_t stream) {
  const float* node_attrs = (const float*)d_in[0];
  const float* node_feats = (const float*)d_in[1];
  const float* edge_attrs = (const float*)d_in[2];
  const float* edge_feats = (const float*)d_in[3];
  const int*   edge_index = (const int*)d_in[4];
  const float* W_up0 = (const float*)d_in[5];
  const float* W_up1 = (const float*)d_in[6];
  const float* R0 = (const float*)d_in[7];
  const float* R1 = (const float*)d_in[8];
  const float* R2 = (const float*)d_in[9];
  const float* R3 = (const float*)d_in[10];
  const float* Wd  = (const float*)d_in[11];
  const float* Wl0 = (const float*)d_in[12];
  const float* Wl1 = (const float*)d_in[13];
  const float* Ws0 = (const float*)d_in[14];
  const float* Ws1 = (const float*)d_in[15];
  float* out = (float*)d_out;

  // Workspace layout (H region kept float-sized, used as half):
  // H | M | density | counts | offsets | cursor | snd_s | rcv_s |
  // ea_s | Bsw0 | Bsw1 | R1a | R2a | R3a (ushort) | ef_s
  __half* Hh = (__half*)d_ws;
  float* M = (float*)d_ws + (size_t)N_NODES * 512;
  float* density = M + (size_t)N_NODES * 1024;
  int* counts  = (int*)(density + 10000);
  int* offsets = counts + 10016;
  int* cursor  = offsets + 10016;
  int* snd_s   = cursor + 10016;
  int* rcv_s   = snd_s + N_EDGES;
  float* ea_s  = (float*)(rcv_s + N_EDGES);
  unsigned short* Bsw0 = (unsigned short*)(ea_s + (size_t)N_EDGES * 4);
  unsigned short* Bsw1 = Bsw0 + 1280 * 128;
  unsigned short* R1a  = Bsw1 + 1280 * 128;
  unsigned short* R2a  = R1a + 64 * 64;
  unsigned short* R3a  = R2a + 64 * 64;
  float* ef_s  = (float*)(R3a + 64 * 512);

  // zero M + density + counts (contiguous)
  hipMemsetAsync(M, 0, ((size_t)N_NODES * 1024 + 10000 + 10016) * sizeof(float),
                 stream);

  k_node_up<<<N_NODES / 8, 256, 0, stream>>>(node_feats, W_up0, W_up1, Hh);
  k_cvt<<<640, 256, 0, stream>>>(Ws0, Ws1, Bsw0, Bsw1);
  k_cvt_w<<<16, 256, 0, stream>>>(R1, R1a, 64 * 64, 6, 2);
  k_cvt_w<<<16, 256, 0, stream>>>(R2, R2a, 64 * 64, 6, 2);
  k_cvt_w<<<128, 256, 0, stream>>>(R3, R3a, 64 * 512, 9, 2);
  k_hist<<<(N_EDGES + 255) / 256, 256, 0, stream>>>(edge_index, counts);
  k_scan<<<1, 1024, 0, stream>>>(counts, offsets, cursor);
  k_scatter<<<(N_EDGES + 255) / 256, 256, 0, stream>>>(
      edge_index, edge_attrs, edge_feats, cursor, snd_s, rcv_s, ea_s, ef_s);
  k_mlp_msg<<<N_EDGES / 128, 256, 0, stream>>>(ef_s, ea_s, snd_s, rcv_s,
                                               offsets, R0, R1a, R2a, R3a, Wd,
                                               Hh, M, density);
  k_out<<<N_NODES / 8, 256, 0, stream>>>(M, density, Wl0, Wl1, out);
  k_skip_mfma<<<157 + 469, 256, 0, stream>>>(node_feats, node_attrs, Bsw0, Bsw1,
                                             out + (size_t)N_NODES * 512);
}